// Round 4
// baseline (159.801 us; speedup 1.0000x reference)
//
#include <hip/hip_runtime.h>
#include <hip/hip_bf16.h>
#include <cstdint>

#define B_   2
#define L_   2048
#define DIM_ 1024
#define H_   16
#define HD_  64
#define M_   (B_ * L_)    // 4096
#define N3_  (3 * DIM_)   // 3072

typedef unsigned short ushort_t;
typedef __bf16 bf16x8 __attribute__((ext_vector_type(8)));
typedef float  f32x4  __attribute__((ext_vector_type(4)));
typedef float  f32x16 __attribute__((ext_vector_type(16)));
typedef unsigned u32x2_t __attribute__((ext_vector_type(2)));

// native cast -> compiler emits v_cvt_pk_bf16_f32 for adjacent pairs (RTNE)
__device__ __forceinline__ unsigned short f2b(float f) {
  return __builtin_bit_cast(unsigned short, (__bf16)f);
}
__device__ __forceinline__ float b2f(unsigned short s) {
  unsigned u = ((unsigned)s) << 16;
  return __builtin_bit_cast(float, u);
}
__device__ __forceinline__ float fmax3(float a, float b, float c) {
  return fmaxf(fmaxf(a, b), c);   // fuses to v_max3_f32
}

// {a,b} -> a' = [a_lo | b_lo], b' = [a_hi | b_hi]  (lane halves)
__device__ __forceinline__ void plswap(unsigned &a, unsigned &b) {
#if defined(__has_builtin) && __has_builtin(__builtin_amdgcn_permlane32_swap)
  u32x2_t r = __builtin_amdgcn_permlane32_swap(a, b, false, false);
  a = r[0]; b = r[1];
#else
  unsigned sa = (unsigned)__shfl_xor((int)a, 32);
  unsigned sb = (unsigned)__shfl_xor((int)b, 32);
  bool hi = (threadIdx.x & 32) != 0;
  unsigned na = hi ? sb : a;
  unsigned nb = hi ? b : sa;
  a = na; b = nb;
#endif
}

typedef const __attribute__((address_space(1))) void* as1cp;
typedef __attribute__((address_space(3))) void* as3p;
__device__ __forceinline__ void gload_lds16(const void* g, void* l) {
  __builtin_amdgcn_global_load_lds((as1cp)g, (as3p)l, 16, 0, 0);
}

// ---------------- elementwise f32 -> bf16 ----------------
__global__ __launch_bounds__(256)
void conv_bf16(const float* __restrict__ in, ushort_t* __restrict__ out, int n4) {
  int i = blockIdx.x * 256 + threadIdx.x;
  if (i >= n4) return;
  float4 v = *(const float4*)&in[(size_t)i * 4];
  ushort4 o;
  o.x = f2b(v.x); o.y = f2b(v.y); o.z = f2b(v.z); o.w = f2b(v.w);
  *(ushort4*)&out[(size_t)i * 4] = o;
}

// ---------------- f32 [R][C] -> bf16 [C][R] transpose ----------------
__global__ __launch_bounds__(256)
void transpose_conv(const float* __restrict__ in, ushort_t* __restrict__ out,
                    int R, int C) {
  __shared__ float tile[64][65];
  const int t = threadIdx.x;
  const int r0 = blockIdx.y * 64, c0 = blockIdx.x * 64;
#pragma unroll
  for (int p = 0; p < 4; ++p) {
    int r = (t >> 4) + p * 16;
    int c = (t & 15) * 4;
    float4 v = *(const float4*)&in[(size_t)(r0 + r) * C + (c0 + c)];
    tile[r][c + 0] = v.x; tile[r][c + 1] = v.y;
    tile[r][c + 2] = v.z; tile[r][c + 3] = v.w;
  }
  __syncthreads();
#pragma unroll
  for (int p = 0; p < 4; ++p) {
    int cc = (t >> 4) + p * 16;
    int r  = (t & 15) * 4;
    ushort4 o;
    o.x = f2b(tile[r + 0][cc]); o.y = f2b(tile[r + 1][cc]);
    o.z = f2b(tile[r + 2][cc]); o.w = f2b(tile[r + 3][cc]);
    *(ushort4*)&out[(size_t)(c0 + cc) * R + (r0 + r)] = o;
  }
}

// ---------------- rope cos/sin table [L][32] ----------------
__global__ __launch_bounds__(256)
void rope_tab(float* __restrict__ cosT, float* __restrict__ sinT) {
  int idx = blockIdx.x * 256 + threadIdx.x;   // 65536 = 2048*32
  int l = idx >> 5, d = idx & 31;
  float inv_freq = expf(-((float)(2 * d) / 64.f) * logf(10000.f));
  float ang = (float)l * inv_freq;
  cosT[idx] = cosf(ang);
  sinT[idx] = sinf(ang);
}

// ---------------- GEMM: A[M][K] bf16 @ BT[N][K] bf16 ----------------
// 128x128 tile, BK=32, 4 waves (2x2), 16x16x32 MFMA, global_load_lds staging.
// MODE 0: QKV gemm -> q,k cols [0,2048) to Cqk[row][ldc]; V cols [2048,3072)
//         transposed to vt[b][d][l].  MODE 1: f32 out + bias.
template <int MODE>
__global__ __launch_bounds__(256)
void gemm_bt(const ushort_t* __restrict__ A, const ushort_t* __restrict__ BT,
             void* __restrict__ Cout, ushort_t* __restrict__ vtout,
             const float* __restrict__ bias, int M, int N, int K, int ldc) {
  __shared__ ushort_t As[128 * 32];
  __shared__ ushort_t Bs[128 * 32];
  const int lane = threadIdx.x & 63;
  const int wid  = threadIdx.x >> 6;
  const int wm = wid >> 1, wn = wid & 1;
  const int m0 = blockIdx.y * 128, n0 = blockIdx.x * 128;
  const int ro = lane & 15, kg = lane >> 4;

  f32x4 acc[4][4] = {};

  for (int k0 = 0; k0 < K; k0 += 32) {
    const int cb = wid * 128;
#pragma unroll
    for (int j = 0; j < 2; ++j) {
      int c = cb + j * 64 + lane;
      gload_lds16(A + (size_t)(m0 + (c >> 2)) * K + k0 + (c & 3) * 8,
                  &As[(cb + j * 64) * 8]);
    }
#pragma unroll
    for (int j = 0; j < 2; ++j) {
      int c = cb + j * 64 + lane;
      gload_lds16(BT + (size_t)(n0 + (c >> 2)) * K + k0 + (c & 3) * 8,
                  &Bs[(cb + j * 64) * 8]);
    }
    __syncthreads();
    bf16x8 af[4], bfr[4];
#pragma unroll
    for (int i = 0; i < 4; ++i)
      af[i] = *(const bf16x8*)&As[(wm * 64 + i * 16 + ro) * 32 + kg * 8];
#pragma unroll
    for (int i = 0; i < 4; ++i)
      bfr[i] = *(const bf16x8*)&Bs[(wn * 64 + i * 16 + ro) * 32 + kg * 8];
#pragma unroll
    for (int i = 0; i < 4; ++i)
#pragma unroll
      for (int j = 0; j < 4; ++j)
        acc[i][j] = __builtin_amdgcn_mfma_f32_16x16x32_bf16(af[i], bfr[j],
                                                            acc[i][j], 0, 0, 0);
    __syncthreads();
  }

  if (MODE == 0) {
    if (n0 < 2048) {
#pragma unroll
      for (int i = 0; i < 4; ++i)
#pragma unroll
        for (int r = 0; r < 4; ++r) {
          int row = m0 + wm * 64 + i * 16 + kg * 4 + r;
#pragma unroll
          for (int j = 0; j < 4; ++j) {
            int col = n0 + wn * 64 + j * 16 + ro;
            ((ushort_t*)Cout)[(size_t)row * ldc + col] = f2b(acc[i][j][r]);
          }
        }
    } else {
      // V columns -> vt[b][dg][l], 4 consecutive l per lane packed
#pragma unroll
      for (int i = 0; i < 4; ++i) {
        int rowb = m0 + wm * 64 + i * 16 + kg * 4;
        int bb = rowb >> 11, l = rowb & (L_ - 1);
#pragma unroll
        for (int j = 0; j < 4; ++j) {
          int dg = (n0 - 2048) + wn * 64 + j * 16 + ro;
          ushort4 o;
          o.x = f2b(acc[i][j][0]); o.y = f2b(acc[i][j][1]);
          o.z = f2b(acc[i][j][2]); o.w = f2b(acc[i][j][3]);
          *(ushort4*)&vtout[((size_t)bb * DIM_ + dg) * L_ + l] = o;
        }
      }
    }
  } else {
#pragma unroll
    for (int i = 0; i < 4; ++i)
#pragma unroll
      for (int r = 0; r < 4; ++r) {
        int row = m0 + wm * 64 + i * 16 + kg * 4 + r;
#pragma unroll
        for (int j = 0; j < 4; ++j) {
          int col = n0 + wn * 64 + j * 16 + ro;
          ((float*)Cout)[(size_t)row * ldc + col] = acc[i][j][r] + bias[col];
        }
      }
  }
}

// ---------------- fused per-head RMSNorm + RoPE on q,k (in place) ----------------
// qk layout [token][2048]: q cols [0,1024), k cols [1024,2048).
// Q additionally prescaled by 0.125*log2(e) so attention uses exp2 directly.
__global__ __launch_bounds__(256)
void rmsrope(ushort_t* __restrict__ qk, const float* __restrict__ qs,
             const float* __restrict__ ks, const float* __restrict__ cosT,
             const float* __restrict__ sinT) {
  const int t = blockIdx.x;          // token 0..4095
  const int l = t & (L_ - 1);
  const int j = threadIdx.x & 15;    // 16 threads per head
  const int h = threadIdx.x >> 4;
  const int dd = (j & 7) * 4;
  float4 cv = *(const float4*)&cosT[l * 32 + dd];
  float4 sv = *(const float4*)&sinT[l * 32 + dd];
  const float sgn = (j < 8) ? -1.f : 1.f;
#pragma unroll
  for (int ic = 0; ic < 2; ++ic) {
    const float qsc = (ic == 0) ? 0.125f * 1.44269504088896341f : 1.f;
    ushort_t* base = qk + (size_t)t * 2048 + ic * DIM_ + h * HD_ + j * 4;
    ushort4 raw = *(const ushort4*)base;
    float x0 = b2f(raw.x), x1 = b2f(raw.y), x2 = b2f(raw.z), x3 = b2f(raw.w);
    float ss = x0 * x0 + x1 * x1 + x2 * x2 + x3 * x3;
    ss += __shfl_xor(ss, 1); ss += __shfl_xor(ss, 2);
    ss += __shfl_xor(ss, 4); ss += __shfl_xor(ss, 8);
    float inv = rsqrtf(ss * (1.f / 64.f) + 1e-6f);
    const float* scp = (ic == 0 ? qs : ks) + j * 4;
    float4 sc = *(const float4*)scp;
    x0 *= inv * sc.x; x1 *= inv * sc.y; x2 *= inv * sc.z; x3 *= inv * sc.w;
    float y0 = __shfl_xor(x0, 8), y1 = __shfl_xor(x1, 8);
    float y2 = __shfl_xor(x2, 8), y3 = __shfl_xor(x3, 8);
    ushort4 o;
    o.x = f2b((x0 * cv.x + sgn * y0 * sv.x) * qsc);
    o.y = f2b((x1 * cv.y + sgn * y1 * sv.y) * qsc);
    o.z = f2b((x2 * cv.z + sgn * y2 * sv.z) * qsc);
    o.w = f2b((x3 * cv.w + sgn * y3 * sv.w) * qsc);
    *(ushort4*)base = o;
  }
}

// ---------------- flash attention, 32x32 MFMA, P-in-register, K-split ----------------
// SPLIT=1: grid (L/128, H, B*2), each block does half the K range; writes
// normalized f32 partial O + (m,l) per (tok,h). SPLIT=0: single pass -> bf16 O.
// Swapped QK^T via mfma_f32_32x32x16: D[k][q], col=lane&31=q; P redistributed
// in-register via cvt_pk + permlane32_swap; row-sum on the matrix pipe via
// ones-A MFMA (laccv[0] = full sum, no cross-half shfl); defer-max THR=8.
template <int SPLIT>
__global__ __launch_bounds__(256)
void flash_attn(const ushort_t* __restrict__ qk, const ushort_t* __restrict__ vt,
                ushort_t* __restrict__ O, float* __restrict__ Opart,
                float* __restrict__ Ml) {
  const int qt = blockIdx.x, h = blockIdx.y;
  const int b  = SPLIT ? (int)(blockIdx.z >> 1) : (int)blockIdx.z;
  const int ks = SPLIT ? (int)(blockIdx.z & 1) : 0;
  const int ktBeg = SPLIT ? ks * (L_ / 128) : 0;     // 16 tiles per split
  const int ktEnd = SPLIT ? ktBeg + (L_ / 128) : (L_ / 64);
  const int lane = threadIdx.x & 63, wid = threadIdx.x >> 6;
  const int lq = lane & 31;          // q (QK) / d' (PV A) / col index
  const int hi = lane >> 5;          // lane-half: k-slice half selector
  const int q0 = qt * 128;
  const size_t tok0 = (size_t)b * L_;
  const ushort_t* qb = qk + tok0 * 2048 + h * HD_;
  const ushort_t* kb = qb + DIM_;
  const ushort_t* vb = vt + ((size_t)b * DIM_ + h * HD_) * L_;

  __shared__ ushort_t Ks[2][4096];   // [kpos 64][d 64], 16B-chunk XOR swizzle
  __shared__ ushort_t Vs[2][4096];   // [d 64][kpos 64], same swizzle

  // staging: each thread 2x K + 2x V chunks, source pre-swizzled (rule 21)
  const int srow0 = wid * 16 + (lane >> 3);
  const int sch   = lane & 7;
  auto STAGE = [&](int bufi, int kt) {
#pragma unroll
    for (int j = 0; j < 2; ++j) {
      int row = srow0 + j * 8;
      int sc  = sch ^ (row & 7);
      gload_lds16(kb + (size_t)(kt * 64 + row) * 2048 + sc * 8,
                  &Ks[bufi][wid * 1024 + j * 512]);
      gload_lds16(vb + (size_t)row * L_ + kt * 64 + sc * 8,
                  &Vs[bufi][wid * 1024 + j * 512]);
    }
  };

  // Q fragments: B-operand of QK^T.  qf[s]: Q[q=lq][d = 16s + hi*8 + j]
  bf16x8 qf[4];
  {
    const ushort_t* gp = qb + (size_t)(q0 + wid * 32 + lq) * 2048;
#pragma unroll
    for (int s = 0; s < 4; ++s)
      qf[s] = *(const bf16x8*)(gp + s * 16 + hi * 8);
  }

  // ones A-operand: row-sum of P on the matrix pipe
  bf16x8 onesv;
#pragma unroll
  for (int i = 0; i < 8; ++i) onesv[i] = (__bf16)1.0f;

  // swizzled chunk byte-offsets (ushort units), shared by K d-slices and V
  // k-slices: chunk = (2*idx + hi) ^ (lq & 7)
  int chs[4];
#pragma unroll
  for (int s = 0; s < 4; ++s) chs[s] = ((2 * s + hi) ^ (lq & 7)) * 8;

  f32x16 oaccT[2] = {};              // [dtile] D[row=d'][col=q=lq]
  f32x16 laccv = {};                 // row-sum accumulator; only [0] consumed
  float mrow = -1e30f;               // per-lane running max: q = lq

  STAGE(0, ktBeg);
  __syncthreads();

  auto TILE = [&](int bi, int kt) {
    if (kt + 1 < ktEnd) STAGE(bi ^ 1, kt + 1);
    const ushort_t* kb0 = &Ks[bi][lq * 64];
    const ushort_t* vb0 = &Vs[bi][lq * 64];

    // S^T tiles: st[t] = K[ktile t rows] . Q^T  -> D[kpos][q]
    f32x16 st[2];
    __builtin_amdgcn_s_setprio(1);
#pragma unroll
    for (int t = 0; t < 2; ++t) {
      f32x16 z = {};
#pragma unroll
      for (int s = 0; s < 4; ++s) {
        bf16x8 kf = *(const bf16x8*)(kb0 + t * 2048 + chs[s]);
        z = __builtin_amdgcn_mfma_f32_32x32x16_bf16(kf, qf[s], z, 0, 0, 0);
      }
      st[t] = z;
    }
    __builtin_amdgcn_s_setprio(0);

    // row max via max3 tree (16 ops) + cross-half
    float m01 = fmax3(st[0][0],  st[0][1],  st[0][2]);
    float m02 = fmax3(st[0][3],  st[0][4],  st[0][5]);
    float m03 = fmax3(st[0][6],  st[0][7],  st[0][8]);
    float m04 = fmax3(st[0][9],  st[0][10], st[0][11]);
    float m05 = fmax3(st[0][12], st[0][13], st[0][14]);
    float m06 = fmax3(st[0][15], st[1][0],  st[1][1]);
    float m07 = fmax3(st[1][2],  st[1][3],  st[1][4]);
    float m08 = fmax3(st[1][5],  st[1][6],  st[1][7]);
    float m09 = fmax3(st[1][8],  st[1][9],  st[1][10]);
    float m10 = fmax3(st[1][11], st[1][12], st[1][13]);
    float m11 = fmaxf(st[1][14], st[1][15]);
    float n1 = fmax3(m01, m02, m03);
    float n2 = fmax3(m04, m05, m06);
    float n3 = fmax3(m07, m08, m09);
    float n4 = fmax3(m10, m11, n1);
    float pmw = fmax3(n2, n3, n4);
    float pm  = fmaxf(pmw, __shfl_xor(pmw, 32));

    // defer-max: rescale only when some row's max grew by >8 (log2 domain;
    // P then bounded by 2^8, f32 accum has ample headroom)
    if (__any(pm > mrow + 8.f)) {
      float mn = fmaxf(mrow, pm);
      float alpha = __builtin_amdgcn_exp2f(mrow - mn);
      mrow = mn;
      laccv[0] *= alpha;             // only reg 0 is ever consumed
#pragma unroll
      for (int dt = 0; dt < 2; ++dt)
#pragma unroll
        for (int r = 0; r < 16; ++r) oaccT[dt][r] *= alpha;
    }

    // P = exp2(S - m), packed bf16 pairs (row-sum now done on matrix pipe)
    unsigned pk[2][8];
#pragma unroll
    for (int t = 0; t < 2; ++t)
#pragma unroll
      for (int p = 0; p < 8; ++p) {
        float e0 = __builtin_amdgcn_exp2f(st[t][2 * p]     - mrow);
        float e1 = __builtin_amdgcn_exp2f(st[t][2 * p + 1] - mrow);
        pk[t][p] = (unsigned)f2b(e0) | ((unsigned)f2b(e1) << 16);
      }

    // PV: redistribute P via permlane32_swap into B-fragments, then
    // oaccT[dt] += mfma(V^T-frag, P-frag); laccv += mfma(ones, P-frag).
    __builtin_amdgcn_s_setprio(1);
#pragma unroll
    for (int t = 0; t < 2; ++t)
#pragma unroll
      for (int blk = 0; blk < 2; ++blk) {
        unsigned w0 = pk[t][4 * blk + 0], w1 = pk[t][4 * blk + 1];
        unsigned w2 = pk[t][4 * blk + 2], w3 = pk[t][4 * blk + 3];
        plswap(w0, w2);   // -> {j0j1, j4j5}
        plswap(w1, w3);   // -> {j2j3, j6j7}
        uint4 bw; bw.x = w0; bw.y = w1; bw.z = w2; bw.w = w3;
        bf16x8 pf = __builtin_bit_cast(bf16x8, bw);
        const int sg = 2 * t + blk;
        laccv = __builtin_amdgcn_mfma_f32_32x32x16_bf16(onesv, pf, laccv, 0, 0, 0);
#pragma unroll
        for (int dt = 0; dt < 2; ++dt) {
          bf16x8 vf = *(const bf16x8*)(vb0 + dt * 2048 + chs[sg]);
          oaccT[dt] = __builtin_amdgcn_mfma_f32_32x32x16_bf16(vf, pf,
                                                              oaccT[dt], 0, 0, 0);
        }
      }
    __builtin_amdgcn_s_setprio(0);

    __syncthreads();   // drains vmcnt: stage(kt+1) complete; buffers safe
  };

  for (int kt = ktBeg; kt < ktEnd; kt += 2) {
    TILE(0, kt);
    TILE(1, kt + 1);
  }

  // epilogue: all lane-local (q = lq); laccv[0] = full row sum (MFMA sums
  // the whole K-slice, both lane halves included)
  const float linv = 1.f / laccv[0];
  const int tok = (int)tok0 + q0 + wid * 32 + lq;
  if (SPLIT) {
    float* op = Opart + ((size_t)ks * M_ + tok) * DIM_ + h * HD_;
#pragma unroll
    for (int dt = 0; dt < 2; ++dt)
#pragma unroll
      for (int g4 = 0; g4 < 4; ++g4) {
        int d0 = dt * 32 + g4 * 8 + hi * 4;
        float4 o4;
        o4.x = oaccT[dt][4 * g4 + 0] * linv;
        o4.y = oaccT[dt][4 * g4 + 1] * linv;
        o4.z = oaccT[dt][4 * g4 + 2] * linv;
        o4.w = oaccT[dt][4 * g4 + 3] * linv;
        *(float4*)(op + d0) = o4;
      }
    if (hi == 0) {
      float2 ml; ml.x = mrow; ml.y = laccv[0];
      *(float2*)&Ml[(((size_t)ks * M_ + tok) * H_ + h) * 2] = ml;
    }
  } else {
    ushort_t* obp = O + (size_t)tok * DIM_ + h * HD_;
#pragma unroll
    for (int dt = 0; dt < 2; ++dt)
#pragma unroll
      for (int g4 = 0; g4 < 4; ++g4) {
        int d0 = dt * 32 + g4 * 8 + hi * 4;
        ushort4 o4;
        o4.x = f2b(oaccT[dt][4 * g4 + 0] * linv);
        o4.y = f2b(oaccT[dt][4 * g4 + 1] * linv);
        o4.z = f2b(oaccT[dt][4 * g4 + 2] * linv);
        o4.w = f2b(oaccT[dt][4 * g4 + 3] * linv);
        *(ushort4*)(obp + d0) = o4;
      }
  }
}

// ---------------- combine two K-split partials -> bf16 O ----------------
// O = (w0*O0 + w1*O1), w_i = l_i*2^(m_i-M) / sum  (partials are normalized)
__global__ __launch_bounds__(256)
void attn_combine(const float* __restrict__ Opart, const float* __restrict__ Ml,
                  ushort_t* __restrict__ O) {
  int idx = blockIdx.x * 256 + threadIdx.x;   // 1,048,576 total
  int dg  = idx & 15;
  int rest = idx >> 4;
  int h   = rest & 15;
  int tok = rest >> 4;
  float2 ml0 = *(const float2*)&Ml[(((size_t)0 * M_ + tok) * H_ + h) * 2];
  float2 ml1 = *(const float2*)&Ml[(((size_t)1 * M_ + tok) * H_ + h) * 2];
  float mM = fmaxf(ml0.x, ml1.x);
  float w0 = ml0.y * __builtin_amdgcn_exp2f(ml0.x - mM);
  float w1 = ml1.y * __builtin_amdgcn_exp2f(ml1.x - mM);
  float inv = 1.f / (w0 + w1);
  w0 *= inv; w1 *= inv;
  size_t off = (size_t)tok * DIM_ + h * HD_ + dg * 4;
  float4 a = *(const float4*)&Opart[off];
  float4 c = *(const float4*)&Opart[(size_t)M_ * DIM_ + off];
  ushort4 o;
  o.x = f2b(a.x * w0 + c.x * w1);
  o.y = f2b(a.y * w0 + c.y * w1);
  o.z = f2b(a.z * w0 + c.z * w1);
  o.w = f2b(a.w * w0 + c.w * w1);
  *(ushort4*)&O[off] = o;
}

// ---------------- launch ----------------
extern "C" void kernel_launch(void* const* d_in, const int* in_sizes, int n_in,
                              void* d_out, int out_size, void* d_ws, size_t ws_size,
                              hipStream_t stream) {
  const float* x     = (const float*)d_in[0];
  const float* Wqkv  = (const float*)d_in[1];
  const float* qs    = (const float*)d_in[2];
  const float* ks    = (const float*)d_in[3];
  const float* Wproj = (const float*)d_in[4];
  const float* bproj = (const float*)d_in[5];
  float* out = (float*)d_out;

  char* ws = (char*)d_ws;
  ushort_t* xb     = (ushort_t*)(ws);                                  // 8 MB
  ushort_t* WqkvT  = (ushort_t*)(ws + (size_t)(8u << 20));             // 6 MB
  ushort_t* WprojT = (ushort_t*)(ws + (size_t)(14u << 20));            // 2 MB
  ushort_t* qkb    = (ushort_t*)(ws + (size_t)(16u << 20));            // 16 MB [4096][2048]
  ushort_t* vtb    = (ushort_t*)(ws + (size_t)(32u << 20));            // 8 MB  [2][1024][2048]
  float*    cosT   = (float*)(ws + (size_t)(40u << 20));               // 256 KB
  float*    sinT   = (float*)(ws + (size_t)(40u << 20) + (256u << 10));// 256 KB
  ushort_t* ob     = (ushort_t*)(ws + (size_t)(41u << 20));            // 8 MB
  float*    Opart  = (float*)(ws + (size_t)(49u << 20));               // 32 MB [2][4096][1024] f32
  float*    Ml     = (float*)(ws + (size_t)(81u << 20));               // 1 MB  [2][4096][16][2] f32

  conv_bf16<<<4096, 256, 0, stream>>>(x, xb, M_ * DIM_ / 4);
  transpose_conv<<<dim3(48, 16), 256, 0, stream>>>(Wqkv, WqkvT, DIM_, N3_);
  transpose_conv<<<dim3(16, 16), 256, 0, stream>>>(Wproj, WprojT, DIM_, DIM_);
  rope_tab<<<256, 256, 0, stream>>>(cosT, sinT);
  gemm_bt<0><<<dim3(24, 32), 256, 0, stream>>>(xb, WqkvT, qkb, vtb, nullptr,
                                               M_, N3_, DIM_, 2048);
  rmsrope<<<4096, 256, 0, stream>>>(qkb, qs, ks, cosT, sinT);
  if (ws_size >= ((size_t)83u << 20)) {
    flash_attn<1><<<dim3(16, 16, 4), 256, 0, stream>>>(qkb, vtb, nullptr,
                                                       Opart, Ml);
    attn_combine<<<4096, 256, 0, stream>>>(Opart, Ml, ob);
  } else {
    flash_attn<0><<<dim3(16, 16, 2), 256, 0, stream>>>(qkb, vtb, ob,
                                                       nullptr, nullptr);
  }
  gemm_bt<1><<<dim3(8, 32), 256, 0, stream>>>(ob, WprojT, out, nullptr, bproj,
                                              M_, DIM_, DIM_, DIM_);
}

// Round 5
// 152.678 us; speedup vs baseline: 1.0467x; 1.0467x over previous
//
#include <hip/hip_runtime.h>
#include <hip/hip_bf16.h>
#include <cstdint>

#define B_   2
#define L_   2048
#define DIM_ 1024
#define H_   16
#define HD_  64
#define M_   (B_ * L_)    // 4096
#define N3_  (3 * DIM_)   // 3072

typedef unsigned short ushort_t;
typedef __bf16 bf16x8 __attribute__((ext_vector_type(8)));
typedef float  f32x4  __attribute__((ext_vector_type(4)));
typedef float  f32x16 __attribute__((ext_vector_type(16)));
typedef unsigned u32x2_t __attribute__((ext_vector_type(2)));

// native cast -> compiler emits v_cvt_pk_bf16_f32 for adjacent pairs (RTNE)
__device__ __forceinline__ unsigned short f2b(float f) {
  return __builtin_bit_cast(unsigned short, (__bf16)f);
}
__device__ __forceinline__ float b2f(unsigned short s) {
  unsigned u = ((unsigned)s) << 16;
  return __builtin_bit_cast(float, u);
}
__device__ __forceinline__ float fmax3(float a, float b, float c) {
  return fmaxf(fmaxf(a, b), c);   // fuses to v_max3_f32
}

// {a,b} -> a' = [a_lo | b_lo], b' = [a_hi | b_hi]  (lane halves)
__device__ __forceinline__ void plswap(unsigned &a, unsigned &b) {
#if defined(__has_builtin) && __has_builtin(__builtin_amdgcn_permlane32_swap)
  u32x2_t r = __builtin_amdgcn_permlane32_swap(a, b, false, false);
  a = r[0]; b = r[1];
#else
  unsigned sa = (unsigned)__shfl_xor((int)a, 32);
  unsigned sb = (unsigned)__shfl_xor((int)b, 32);
  bool hi = (threadIdx.x & 32) != 0;
  unsigned na = hi ? sb : a;
  unsigned nb = hi ? b : sa;
  a = na; b = nb;
#endif
}

typedef const __attribute__((address_space(1))) void* as1cp;
typedef __attribute__((address_space(3))) void* as3p;
__device__ __forceinline__ void gload_lds16(const void* g, void* l) {
  __builtin_amdgcn_global_load_lds((as1cp)g, (as3p)l, 16, 0, 0);
}

// ---------------- elementwise f32 -> bf16 ----------------
__global__ __launch_bounds__(256)
void conv_bf16(const float* __restrict__ in, ushort_t* __restrict__ out, int n4) {
  int i = blockIdx.x * 256 + threadIdx.x;
  if (i >= n4) return;
  float4 v = *(const float4*)&in[(size_t)i * 4];
  ushort4 o;
  o.x = f2b(v.x); o.y = f2b(v.y); o.z = f2b(v.z); o.w = f2b(v.w);
  *(ushort4*)&out[(size_t)i * 4] = o;
}

// ---------------- f32 [R][C] -> bf16 [C][R] transpose ----------------
__global__ __launch_bounds__(256)
void transpose_conv(const float* __restrict__ in, ushort_t* __restrict__ out,
                    int R, int C) {
  __shared__ float tile[64][65];
  const int t = threadIdx.x;
  const int r0 = blockIdx.y * 64, c0 = blockIdx.x * 64;
#pragma unroll
  for (int p = 0; p < 4; ++p) {
    int r = (t >> 4) + p * 16;
    int c = (t & 15) * 4;
    float4 v = *(const float4*)&in[(size_t)(r0 + r) * C + (c0 + c)];
    tile[r][c + 0] = v.x; tile[r][c + 1] = v.y;
    tile[r][c + 2] = v.z; tile[r][c + 3] = v.w;
  }
  __syncthreads();
#pragma unroll
  for (int p = 0; p < 4; ++p) {
    int cc = (t >> 4) + p * 16;
    int r  = (t & 15) * 4;
    ushort4 o;
    o.x = f2b(tile[r + 0][cc]); o.y = f2b(tile[r + 1][cc]);
    o.z = f2b(tile[r + 2][cc]); o.w = f2b(tile[r + 3][cc]);
    *(ushort4*)&out[(size_t)(c0 + cc) * R + (r0 + r)] = o;
  }
}

// ---------------- rope cos/sin table [L][32] ----------------
__global__ __launch_bounds__(256)
void rope_tab(float* __restrict__ cosT, float* __restrict__ sinT) {
  int idx = blockIdx.x * 256 + threadIdx.x;   // 65536 = 2048*32
  int l = idx >> 5, d = idx & 31;
  float inv_freq = expf(-((float)(2 * d) / 64.f) * logf(10000.f));
  float ang = (float)l * inv_freq;
  cosT[idx] = cosf(ang);
  sinT[idx] = sinf(ang);
}

// ---------------- GEMM: A[M][K] bf16 @ BT[N][K] bf16 ----------------
// 128x128 tile, BK=32, 4 waves (2x2), 16x16x32 MFMA, global_load_lds staging.
// MODE 0: QKV gemm -> q,k cols [0,2048) to Cqk[row][ldc]; V cols [2048,3072)
//         transposed to vt[b][d][l].  MODE 1: f32 out + bias.
template <int MODE>
__global__ __launch_bounds__(256)
void gemm_bt(const ushort_t* __restrict__ A, const ushort_t* __restrict__ BT,
             void* __restrict__ Cout, ushort_t* __restrict__ vtout,
             const float* __restrict__ bias, int M, int N, int K, int ldc) {
  __shared__ ushort_t As[128 * 32];
  __shared__ ushort_t Bs[128 * 32];
  const int lane = threadIdx.x & 63;
  const int wid  = threadIdx.x >> 6;
  const int wm = wid >> 1, wn = wid & 1;
  const int m0 = blockIdx.y * 128, n0 = blockIdx.x * 128;
  const int ro = lane & 15, kg = lane >> 4;

  f32x4 acc[4][4] = {};

  for (int k0 = 0; k0 < K; k0 += 32) {
    const int cb = wid * 128;
#pragma unroll
    for (int j = 0; j < 2; ++j) {
      int c = cb + j * 64 + lane;
      gload_lds16(A + (size_t)(m0 + (c >> 2)) * K + k0 + (c & 3) * 8,
                  &As[(cb + j * 64) * 8]);
    }
#pragma unroll
    for (int j = 0; j < 2; ++j) {
      int c = cb + j * 64 + lane;
      gload_lds16(BT + (size_t)(n0 + (c >> 2)) * K + k0 + (c & 3) * 8,
                  &Bs[(cb + j * 64) * 8]);
    }
    __syncthreads();
    bf16x8 af[4], bfr[4];
#pragma unroll
    for (int i = 0; i < 4; ++i)
      af[i] = *(const bf16x8*)&As[(wm * 64 + i * 16 + ro) * 32 + kg * 8];
#pragma unroll
    for (int i = 0; i < 4; ++i)
      bfr[i] = *(const bf16x8*)&Bs[(wn * 64 + i * 16 + ro) * 32 + kg * 8];
#pragma unroll
    for (int i = 0; i < 4; ++i)
#pragma unroll
      for (int j = 0; j < 4; ++j)
        acc[i][j] = __builtin_amdgcn_mfma_f32_16x16x32_bf16(af[i], bfr[j],
                                                            acc[i][j], 0, 0, 0);
    __syncthreads();
  }

  if (MODE == 0) {
    if (n0 < 2048) {
#pragma unroll
      for (int i = 0; i < 4; ++i)
#pragma unroll
        for (int r = 0; r < 4; ++r) {
          int row = m0 + wm * 64 + i * 16 + kg * 4 + r;
#pragma unroll
          for (int j = 0; j < 4; ++j) {
            int col = n0 + wn * 64 + j * 16 + ro;
            ((ushort_t*)Cout)[(size_t)row * ldc + col] = f2b(acc[i][j][r]);
          }
        }
    } else {
      // V columns -> vt[b][dg][l], 4 consecutive l per lane packed
#pragma unroll
      for (int i = 0; i < 4; ++i) {
        int rowb = m0 + wm * 64 + i * 16 + kg * 4;
        int bb = rowb >> 11, l = rowb & (L_ - 1);
#pragma unroll
        for (int j = 0; j < 4; ++j) {
          int dg = (n0 - 2048) + wn * 64 + j * 16 + ro;
          ushort4 o;
          o.x = f2b(acc[i][j][0]); o.y = f2b(acc[i][j][1]);
          o.z = f2b(acc[i][j][2]); o.w = f2b(acc[i][j][3]);
          *(ushort4*)&vtout[((size_t)bb * DIM_ + dg) * L_ + l] = o;
        }
      }
    }
  } else {
#pragma unroll
    for (int i = 0; i < 4; ++i)
#pragma unroll
      for (int r = 0; r < 4; ++r) {
        int row = m0 + wm * 64 + i * 16 + kg * 4 + r;
#pragma unroll
        for (int j = 0; j < 4; ++j) {
          int col = n0 + wn * 64 + j * 16 + ro;
          ((float*)Cout)[(size_t)row * ldc + col] = acc[i][j][r] + bias[col];
        }
      }
  }
}

// ---------------- fused per-head RMSNorm + RoPE on q,k (in place) ----------------
// qk layout [token][2048]: q cols [0,1024), k cols [1024,2048).
// Q additionally prescaled by 0.125*log2(e) so attention uses exp2 directly.
__global__ __launch_bounds__(256)
void rmsrope(ushort_t* __restrict__ qk, const float* __restrict__ qs,
             const float* __restrict__ ks, const float* __restrict__ cosT,
             const float* __restrict__ sinT) {
  const int t = blockIdx.x;          // token 0..4095
  const int l = t & (L_ - 1);
  const int j = threadIdx.x & 15;    // 16 threads per head
  const int h = threadIdx.x >> 4;
  const int dd = (j & 7) * 4;
  float4 cv = *(const float4*)&cosT[l * 32 + dd];
  float4 sv = *(const float4*)&sinT[l * 32 + dd];
  const float sgn = (j < 8) ? -1.f : 1.f;
#pragma unroll
  for (int ic = 0; ic < 2; ++ic) {
    const float qsc = (ic == 0) ? 0.125f * 1.44269504088896341f : 1.f;
    ushort_t* base = qk + (size_t)t * 2048 + ic * DIM_ + h * HD_ + j * 4;
    ushort4 raw = *(const ushort4*)base;
    float x0 = b2f(raw.x), x1 = b2f(raw.y), x2 = b2f(raw.z), x3 = b2f(raw.w);
    float ss = x0 * x0 + x1 * x1 + x2 * x2 + x3 * x3;
    ss += __shfl_xor(ss, 1); ss += __shfl_xor(ss, 2);
    ss += __shfl_xor(ss, 4); ss += __shfl_xor(ss, 8);
    float inv = rsqrtf(ss * (1.f / 64.f) + 1e-6f);
    const float* scp = (ic == 0 ? qs : ks) + j * 4;
    float4 sc = *(const float4*)scp;
    x0 *= inv * sc.x; x1 *= inv * sc.y; x2 *= inv * sc.z; x3 *= inv * sc.w;
    float y0 = __shfl_xor(x0, 8), y1 = __shfl_xor(x1, 8);
    float y2 = __shfl_xor(x2, 8), y3 = __shfl_xor(x3, 8);
    ushort4 o;
    o.x = f2b((x0 * cv.x + sgn * y0 * sv.x) * qsc);
    o.y = f2b((x1 * cv.y + sgn * y1 * sv.y) * qsc);
    o.z = f2b((x2 * cv.z + sgn * y2 * sv.z) * qsc);
    o.w = f2b((x3 * cv.w + sgn * y3 * sv.w) * qsc);
    *(ushort4*)base = o;
  }
}

// ---------------- flash attention, 32x32 MFMA, register-diet, K-split ----------------
// SPLIT=1: grid (L/128, H, B*2), half K range per block, bf16 partials + (m,l).
// Register diet for 3 waves/SIMD (launch_bounds(256,3)): serial half-tile
// processing (st 16 live), pk[8], VALU row-sum (no laccv), QK C-init = -mrow
// (folds the exp2 bias subtract into the MFMA), pointer-increment staging.
// Shifted-domain defer-max: trigger pm > 8 (pm = max(S) - mrow_old).
template <int SPLIT>
__global__ __launch_bounds__(256, 3)
void flash_attn(const ushort_t* __restrict__ qk, const ushort_t* __restrict__ vt,
                ushort_t* __restrict__ O, ushort_t* __restrict__ Opart,
                float* __restrict__ Ml) {
  const int qt = blockIdx.x, h = blockIdx.y;
  const int b  = SPLIT ? (int)(blockIdx.z >> 1) : (int)blockIdx.z;
  const int ks = SPLIT ? (int)(blockIdx.z & 1) : 0;
  const int ktBeg = SPLIT ? ks * (L_ / 128) : 0;     // 16 tiles per split
  const int ktEnd = SPLIT ? ktBeg + (L_ / 128) : (L_ / 64);
  const int lane = threadIdx.x & 63, wid = threadIdx.x >> 6;
  const int lq = lane & 31;          // q (QK) / d' (PV A) / col index
  const int hi = lane >> 5;          // lane-half: k-slice half selector
  const int q0 = qt * 128;
  const size_t tok0 = (size_t)b * L_;
  const ushort_t* qb = qk + tok0 * 2048 + h * HD_;
  const ushort_t* kb = qb + DIM_;
  const ushort_t* vb = vt + ((size_t)b * DIM_ + h * HD_) * L_;

  __shared__ ushort_t Ks[2][4096];   // [kpos 64][d 64], 16B-chunk XOR swizzle
  __shared__ ushort_t Vs[2][4096];   // [d 64][kpos 64], same swizzle

  // staging: pointer-increment form.  row offsets j*8 keep the same swizzle
  // channel (j*8 ≡ 0 mod 8), so one sc per thread.
  const int srow0 = wid * 16 + (lane >> 3);
  const int sc    = (lane & 7) ^ (srow0 & 7);
  const ushort_t* kst = kb + (size_t)(ktBeg * 64 + srow0) * 2048 + sc * 8;
  const ushort_t* vst = vb + (size_t)srow0 * L_ + ktBeg * 64 + sc * 8;
  auto STAGE = [&](int bufi) {
    gload_lds16(kst,            &Ks[bufi][wid * 1024]);
    gload_lds16(kst + 8 * 2048, &Ks[bufi][wid * 1024 + 512]);
    gload_lds16(vst,            &Vs[bufi][wid * 1024]);
    gload_lds16(vst + 8 * L_,   &Vs[bufi][wid * 1024 + 512]);
    kst += 64 * 2048;
    vst += 64;
  };

  // Q fragments: B-operand of QK^T.  qf[s]: Q[q=lq][d = 16s + hi*8 + j]
  bf16x8 qf[4];
  {
    const ushort_t* gp = qb + (size_t)(q0 + wid * 32 + lq) * 2048;
#pragma unroll
    for (int s = 0; s < 4; ++s)
      qf[s] = *(const bf16x8*)(gp + s * 16 + hi * 8);
  }

  // swizzled chunk byte-offsets (ushort units), shared by K d-slices and V
  // k-slices: chunk = (2*idx + hi) ^ (lq & 7)
  int chs[4];
#pragma unroll
  for (int s = 0; s < 4; ++s) chs[s] = ((2 * s + hi) ^ (lq & 7)) * 8;

  f32x16 oaccT[2] = {};              // [dtile] D[row=d'][col=q=lq]
  float mrow = 0.f;                  // absolute running max (shifted trigger)
  float lrow = 0.f;                  // per-lane half row-sum

  STAGE(0);
  __syncthreads();

  auto TILE = [&](int bi, bool more) {
    if (more) STAGE(bi ^ 1);
    const ushort_t* kb0 = &Ks[bi][lq * 64];
    const ushort_t* vb0 = &Vs[bi][lq * 64];
#pragma unroll
    for (int t = 0; t < 2; ++t) {
      // QK with C-init = -mrow: st = S - mrow (shifted domain)
      f32x16 st;
#pragma unroll
      for (int i = 0; i < 16; ++i) st[i] = -mrow;
      __builtin_amdgcn_s_setprio(1);
#pragma unroll
      for (int s = 0; s < 4; ++s) {
        bf16x8 kf = *(const bf16x8*)(kb0 + t * 2048 + chs[s]);
        st = __builtin_amdgcn_mfma_f32_32x32x16_bf16(kf, qf[s], st, 0, 0, 0);
      }
      __builtin_amdgcn_s_setprio(0);

      // per-q shifted max over this half-tile (16 vals) + cross-half
      float m1 = fmax3(st[0],  st[1],  st[2]);
      float m2 = fmax3(st[3],  st[4],  st[5]);
      float m3 = fmax3(st[6],  st[7],  st[8]);
      float m4 = fmax3(st[9],  st[10], st[11]);
      float m5 = fmax3(st[12], st[13], st[14]);
      float n1 = fmax3(m1, m2, st[15]);
      float n2 = fmax3(m3, m4, m5);
      float pm = fmaxf(n1, n2);
      pm = fmaxf(pm, __shfl_xor(pm, 32));

      // defer-max: rescale only when max grew by >8 over mrow (log2 domain;
      // P then bounded by 2^8, f32 accum has ample headroom)
      if (__any(pm > 8.f)) {
        float d = fmaxf(pm, 0.f);
        float alpha = __builtin_amdgcn_exp2f(-d);
        mrow += d;
        lrow *= alpha;
#pragma unroll
        for (int dt = 0; dt < 2; ++dt)
#pragma unroll
          for (int r = 0; r < 16; ++r) oaccT[dt][r] *= alpha;
#pragma unroll
        for (int i = 0; i < 16; ++i) st[i] -= d;
      }

      // P = exp2(st), packed bf16 pairs + VALU row-sum (2 partials for ILP)
      unsigned pk[8];
      float rs0 = 0.f, rs1 = 0.f;
#pragma unroll
      for (int p = 0; p < 8; ++p) {
        float e0 = __builtin_amdgcn_exp2f(st[2 * p]);
        float e1 = __builtin_amdgcn_exp2f(st[2 * p + 1]);
        rs0 += e0; rs1 += e1;
        pk[p] = (unsigned)f2b(e0) | ((unsigned)f2b(e1) << 16);
      }
      lrow += rs0 + rs1;

      // PV: redistribute P via permlane32_swap into B-fragments;
      // oaccT[dt] += mfma(V^T-frag, P-frag)
      __builtin_amdgcn_s_setprio(1);
#pragma unroll
      for (int blk = 0; blk < 2; ++blk) {
        unsigned w0 = pk[4 * blk + 0], w1 = pk[4 * blk + 1];
        unsigned w2 = pk[4 * blk + 2], w3 = pk[4 * blk + 3];
        plswap(w0, w2);   // -> {j0j1, j4j5}
        plswap(w1, w3);   // -> {j2j3, j6j7}
        uint4 bw; bw.x = w0; bw.y = w1; bw.z = w2; bw.w = w3;
        bf16x8 pf = __builtin_bit_cast(bf16x8, bw);
        const int sg = 2 * t + blk;
#pragma unroll
        for (int dt = 0; dt < 2; ++dt) {
          bf16x8 vf = *(const bf16x8*)(vb0 + dt * 2048 + chs[sg]);
          oaccT[dt] = __builtin_amdgcn_mfma_f32_32x32x16_bf16(vf, pf,
                                                              oaccT[dt], 0, 0, 0);
        }
      }
      __builtin_amdgcn_s_setprio(0);
    }
    __syncthreads();   // drains vmcnt: stage(next) complete; buffers safe
  };

  const int NT = ktEnd - ktBeg;      // 16 (split) or 32 (single), even
  for (int it = 0; it < NT; it += 2) {
    TILE(0, it + 1 < NT);
    TILE(1, it + 2 < NT);
  }

  // epilogue: lane-local (q = lq); full row-sum needs cross-half add
  lrow += __shfl_xor(lrow, 32);
  const float linv = 1.f / lrow;
  const int tok = (int)tok0 + q0 + wid * 32 + lq;
  ushort_t* obp = (SPLIT ? Opart + (size_t)ks * M_ * DIM_ : O)
                  + (size_t)tok * DIM_ + h * HD_;
#pragma unroll
  for (int dt = 0; dt < 2; ++dt)
#pragma unroll
    for (int g4 = 0; g4 < 4; ++g4) {
      int d0 = dt * 32 + g4 * 8 + hi * 4;
      ushort4 o4;
      o4.x = f2b(oaccT[dt][4 * g4 + 0] * linv);
      o4.y = f2b(oaccT[dt][4 * g4 + 1] * linv);
      o4.z = f2b(oaccT[dt][4 * g4 + 2] * linv);
      o4.w = f2b(oaccT[dt][4 * g4 + 3] * linv);
      *(ushort4*)(obp + d0) = o4;
    }
  if (SPLIT && hi == 0) {
    float2 ml; ml.x = mrow; ml.y = lrow;
    *(float2*)&Ml[(((size_t)ks * M_ + tok) * H_ + h) * 2] = ml;
  }
}

// ---------------- combine two K-split partials (bf16) -> bf16 O ----------------
// O = w0*O0 + w1*O1, w_i = l_i*2^(m_i-M) / sum  (partials are normalized)
__global__ __launch_bounds__(256)
void attn_combine(const ushort_t* __restrict__ Opart, const float* __restrict__ Ml,
                  ushort_t* __restrict__ O) {
  int idx = blockIdx.x * 256 + threadIdx.x;   // 524288 threads, 8 bf16 each
  int c   = idx & 127;                        // chunk-of-8 within row
  int tok = idx >> 7;
  int h   = c >> 3;
  float2 ml0 = *(const float2*)&Ml[(((size_t)0 * M_ + tok) * H_ + h) * 2];
  float2 ml1 = *(const float2*)&Ml[(((size_t)1 * M_ + tok) * H_ + h) * 2];
  float mM = fmaxf(ml0.x, ml1.x);
  float w0 = ml0.y * __builtin_amdgcn_exp2f(ml0.x - mM);
  float w1 = ml1.y * __builtin_amdgcn_exp2f(ml1.x - mM);
  float inv = 1.f / (w0 + w1);
  w0 *= inv; w1 *= inv;
  size_t off = (size_t)tok * DIM_ + c * 8;
  uint4 a = *(const uint4*)&Opart[off];
  uint4 d = *(const uint4*)&Opart[(size_t)M_ * DIM_ + off];
  auto mix = [&](unsigned ua, unsigned ud) -> unsigned {
    float a0 = b2f((unsigned short)(ua & 0xffff)), a1 = b2f((unsigned short)(ua >> 16));
    float d0 = b2f((unsigned short)(ud & 0xffff)), d1 = b2f((unsigned short)(ud >> 16));
    unsigned r0 = f2b(a0 * w0 + d0 * w1), r1 = f2b(a1 * w0 + d1 * w1);
    return r0 | (r1 << 16);
  };
  uint4 o;
  o.x = mix(a.x, d.x); o.y = mix(a.y, d.y);
  o.z = mix(a.z, d.z); o.w = mix(a.w, d.w);
  *(uint4*)&O[off] = o;
}

// ---------------- launch ----------------
extern "C" void kernel_launch(void* const* d_in, const int* in_sizes, int n_in,
                              void* d_out, int out_size, void* d_ws, size_t ws_size,
                              hipStream_t stream) {
  const float* x     = (const float*)d_in[0];
  const float* Wqkv  = (const float*)d_in[1];
  const float* qs    = (const float*)d_in[2];
  const float* ks    = (const float*)d_in[3];
  const float* Wproj = (const float*)d_in[4];
  const float* bproj = (const float*)d_in[5];
  float* out = (float*)d_out;

  char* ws = (char*)d_ws;
  ushort_t* xb     = (ushort_t*)(ws);                                  // 8 MB
  ushort_t* WqkvT  = (ushort_t*)(ws + (size_t)(8u << 20));             // 6 MB
  ushort_t* WprojT = (ushort_t*)(ws + (size_t)(14u << 20));            // 2 MB
  ushort_t* qkb    = (ushort_t*)(ws + (size_t)(16u << 20));            // 16 MB [4096][2048]
  ushort_t* vtb    = (ushort_t*)(ws + (size_t)(32u << 20));            // 8 MB  [2][1024][2048]
  float*    cosT   = (float*)(ws + (size_t)(40u << 20));               // 256 KB
  float*    sinT   = (float*)(ws + (size_t)(40u << 20) + (256u << 10));// 256 KB
  ushort_t* ob     = (ushort_t*)(ws + (size_t)(41u << 20));            // 8 MB
  ushort_t* Opart  = (ushort_t*)(ws + (size_t)(49u << 20));            // 16 MB [2][4096][1024] bf16
  float*    Ml     = (float*)(ws + (size_t)(65u << 20));               // 1 MB  [2][4096][16][2] f32

  conv_bf16<<<4096, 256, 0, stream>>>(x, xb, M_ * DIM_ / 4);
  transpose_conv<<<dim3(48, 16), 256, 0, stream>>>(Wqkv, WqkvT, DIM_, N3_);
  transpose_conv<<<dim3(16, 16), 256, 0, stream>>>(Wproj, WprojT, DIM_, DIM_);
  rope_tab<<<256, 256, 0, stream>>>(cosT, sinT);
  gemm_bt<0><<<dim3(24, 32), 256, 0, stream>>>(xb, WqkvT, qkb, vtb, nullptr,
                                               M_, N3_, DIM_, 2048);
  rmsrope<<<4096, 256, 0, stream>>>(qkb, qs, ks, cosT, sinT);
  if (ws_size >= ((size_t)66u << 20)) {
    flash_attn<1><<<dim3(16, 16, 4), 256, 0, stream>>>(qkb, vtb, nullptr,
                                                       Opart, Ml);
    attn_combine<<<2048, 256, 0, stream>>>(Opart, Ml, ob);
  } else {
    flash_attn<0><<<dim3(16, 16, 2), 256, 0, stream>>>(qkb, vtb, ob,
                                                       nullptr, nullptr);
  }
  gemm_bt<1><<<dim3(8, 32), 256, 0, stream>>>(ob, WprojT, out, nullptr, bproj,
                                              M_, DIM_, DIM_, DIM_);
}

// Round 6
// 145.859 us; speedup vs baseline: 1.0956x; 1.0467x over previous
//
#include <hip/hip_runtime.h>
#include <hip/hip_bf16.h>
#include <cstdint>

#define B_   2
#define L_   2048
#define DIM_ 1024
#define H_   16
#define HD_  64
#define M_   (B_ * L_)    // 4096
#define N3_  (3 * DIM_)   // 3072

typedef unsigned short ushort_t;
typedef __bf16 bf16x8 __attribute__((ext_vector_type(8)));
typedef float  f32x4  __attribute__((ext_vector_type(4)));
typedef float  f32x16 __attribute__((ext_vector_type(16)));
typedef unsigned u32x2_t __attribute__((ext_vector_type(2)));

// native cast -> compiler emits v_cvt_pk_bf16_f32 for adjacent pairs (RTNE)
__device__ __forceinline__ unsigned short f2b(float f) {
  return __builtin_bit_cast(unsigned short, (__bf16)f);
}
__device__ __forceinline__ float b2f(unsigned short s) {
  unsigned u = ((unsigned)s) << 16;
  return __builtin_bit_cast(float, u);
}
__device__ __forceinline__ float fmax3(float a, float b, float c) {
  return fmaxf(fmaxf(a, b), c);   // fuses to v_max3_f32
}

// {a,b} -> a' = [a_lo | b_lo], b' = [a_hi | b_hi]  (lane halves)
__device__ __forceinline__ void plswap(unsigned &a, unsigned &b) {
#if defined(__has_builtin) && __has_builtin(__builtin_amdgcn_permlane32_swap)
  u32x2_t r = __builtin_amdgcn_permlane32_swap(a, b, false, false);
  a = r[0]; b = r[1];
#else
  unsigned sa = (unsigned)__shfl_xor((int)a, 32);
  unsigned sb = (unsigned)__shfl_xor((int)b, 32);
  bool hi = (threadIdx.x & 32) != 0;
  unsigned na = hi ? sb : a;
  unsigned nb = hi ? b : sa;
  a = na; b = nb;
#endif
}

typedef const __attribute__((address_space(1))) void* as1cp;
typedef __attribute__((address_space(3))) void* as3p;
__device__ __forceinline__ void gload_lds16(const void* g, void* l) {
  __builtin_amdgcn_global_load_lds((as1cp)g, (as3p)l, 16, 0, 0);
}

// ---------------- fused preprocessing ----------------
// blk [0,4096):      f32 -> bf16 convert of x (1M float4)
// blk [4096,4864):   Wqkv  f32 [1024][3072] -> bf16 [3072][1024] transpose
// blk [4864,5120):   Wproj f32 [1024][1024] -> bf16 [1024][1024] transpose
// blk [5120,5376):   rope cos/sin table [2048][32]
__global__ __launch_bounds__(256)
void preproc(const float* __restrict__ x, ushort_t* __restrict__ xb,
             const float* __restrict__ Wqkv, ushort_t* __restrict__ WqkvT,
             const float* __restrict__ Wproj, ushort_t* __restrict__ WprojT,
             float* __restrict__ cosT, float* __restrict__ sinT) {
  __shared__ float tile[64][65];
  const int blk = blockIdx.x;
  const int t = threadIdx.x;
  if (blk < 4096) {
    int i = blk * 256 + t;
    float4 v = *(const float4*)&x[(size_t)i * 4];
    ushort4 o;
    o.x = f2b(v.x); o.y = f2b(v.y); o.z = f2b(v.z); o.w = f2b(v.w);
    *(ushort4*)&xb[(size_t)i * 4] = o;
  } else if (blk < 5120) {
    const float* in;
    ushort_t* out;
    int C, bi;
    if (blk < 4864) { in = Wqkv; out = WqkvT; C = 3072; bi = blk - 4096; }
    else            { in = Wproj; out = WprojT; C = 1024; bi = blk - 4864; }
    const int nbx = C >> 6;
    const int bx = bi % nbx, by = bi / nbx;
    const int r0 = by * 64, c0 = bx * 64;
    const int R = 1024;
#pragma unroll
    for (int p = 0; p < 4; ++p) {
      int r = (t >> 4) + p * 16;
      int c = (t & 15) * 4;
      float4 v = *(const float4*)&in[(size_t)(r0 + r) * C + (c0 + c)];
      tile[r][c + 0] = v.x; tile[r][c + 1] = v.y;
      tile[r][c + 2] = v.z; tile[r][c + 3] = v.w;
    }
    __syncthreads();
#pragma unroll
    for (int p = 0; p < 4; ++p) {
      int cc = (t >> 4) + p * 16;
      int r  = (t & 15) * 4;
      ushort4 o;
      o.x = f2b(tile[r + 0][cc]); o.y = f2b(tile[r + 1][cc]);
      o.z = f2b(tile[r + 2][cc]); o.w = f2b(tile[r + 3][cc]);
      *(ushort4*)&out[(size_t)(c0 + cc) * R + (r0 + r)] = o;
    }
  } else {
    int idx = (blk - 5120) * 256 + t;   // 65536 = 2048*32
    int l = idx >> 5, d = idx & 31;
    float inv_freq = expf(-((float)(2 * d) / 64.f) * logf(10000.f));
    float ang = (float)l * inv_freq;
    cosT[idx] = cosf(ang);
    sinT[idx] = sinf(ang);
  }
}

// ---------------- GEMM: A[M][K] bf16 @ BT[N][K] bf16 ----------------
// 128x128 tile, BK=32, 4 waves (2x2), 16x16x32 MFMA, global_load_lds staging.
// MODE 0: QKV gemm -> q,k cols [0,2048) to Cqk[row][ldc]; V cols [2048,3072)
//         transposed to vt[b][d][l].  MODE 1: f32 out + bias.
template <int MODE>
__global__ __launch_bounds__(256)
void gemm_bt(const ushort_t* __restrict__ A, const ushort_t* __restrict__ BT,
             void* __restrict__ Cout, ushort_t* __restrict__ vtout,
             const float* __restrict__ bias, int M, int N, int K, int ldc) {
  __shared__ ushort_t As[128 * 32];
  __shared__ ushort_t Bs[128 * 32];
  const int lane = threadIdx.x & 63;
  const int wid  = threadIdx.x >> 6;
  const int wm = wid >> 1, wn = wid & 1;
  const int m0 = blockIdx.y * 128, n0 = blockIdx.x * 128;
  const int ro = lane & 15, kg = lane >> 4;

  f32x4 acc[4][4] = {};

  for (int k0 = 0; k0 < K; k0 += 32) {
    const int cb = wid * 128;
#pragma unroll
    for (int j = 0; j < 2; ++j) {
      int c = cb + j * 64 + lane;
      gload_lds16(A + (size_t)(m0 + (c >> 2)) * K + k0 + (c & 3) * 8,
                  &As[(cb + j * 64) * 8]);
    }
#pragma unroll
    for (int j = 0; j < 2; ++j) {
      int c = cb + j * 64 + lane;
      gload_lds16(BT + (size_t)(n0 + (c >> 2)) * K + k0 + (c & 3) * 8,
                  &Bs[(cb + j * 64) * 8]);
    }
    __syncthreads();
    bf16x8 af[4], bfr[4];
#pragma unroll
    for (int i = 0; i < 4; ++i)
      af[i] = *(const bf16x8*)&As[(wm * 64 + i * 16 + ro) * 32 + kg * 8];
#pragma unroll
    for (int i = 0; i < 4; ++i)
      bfr[i] = *(const bf16x8*)&Bs[(wn * 64 + i * 16 + ro) * 32 + kg * 8];
#pragma unroll
    for (int i = 0; i < 4; ++i)
#pragma unroll
      for (int j = 0; j < 4; ++j)
        acc[i][j] = __builtin_amdgcn_mfma_f32_16x16x32_bf16(af[i], bfr[j],
                                                            acc[i][j], 0, 0, 0);
    __syncthreads();
  }

  if (MODE == 0) {
    if (n0 < 2048) {
#pragma unroll
      for (int i = 0; i < 4; ++i)
#pragma unroll
        for (int r = 0; r < 4; ++r) {
          int row = m0 + wm * 64 + i * 16 + kg * 4 + r;
#pragma unroll
          for (int j = 0; j < 4; ++j) {
            int col = n0 + wn * 64 + j * 16 + ro;
            ((ushort_t*)Cout)[(size_t)row * ldc + col] = f2b(acc[i][j][r]);
          }
        }
    } else {
      // V columns -> vt[b][dg][l], 4 consecutive l per lane packed
#pragma unroll
      for (int i = 0; i < 4; ++i) {
        int rowb = m0 + wm * 64 + i * 16 + kg * 4;
        int bb = rowb >> 11, l = rowb & (L_ - 1);
#pragma unroll
        for (int j = 0; j < 4; ++j) {
          int dg = (n0 - 2048) + wn * 64 + j * 16 + ro;
          ushort4 o;
          o.x = f2b(acc[i][j][0]); o.y = f2b(acc[i][j][1]);
          o.z = f2b(acc[i][j][2]); o.w = f2b(acc[i][j][3]);
          *(ushort4*)&vtout[((size_t)bb * DIM_ + dg) * L_ + l] = o;
        }
      }
    }
  } else {
#pragma unroll
    for (int i = 0; i < 4; ++i)
#pragma unroll
      for (int r = 0; r < 4; ++r) {
        int row = m0 + wm * 64 + i * 16 + kg * 4 + r;
#pragma unroll
        for (int j = 0; j < 4; ++j) {
          int col = n0 + wn * 64 + j * 16 + ro;
          ((float*)Cout)[(size_t)row * ldc + col] = acc[i][j][r] + bias[col];
        }
      }
  }
}

// ---------------- fused per-head RMSNorm + RoPE on q,k (in place) ----------------
// qk layout [token][2048]: q cols [0,1024), k cols [1024,2048).
// Q additionally prescaled by 0.125*log2(e) so attention uses exp2 directly.
__global__ __launch_bounds__(256)
void rmsrope(ushort_t* __restrict__ qk, const float* __restrict__ qs,
             const float* __restrict__ ks, const float* __restrict__ cosT,
             const float* __restrict__ sinT) {
  const int t = blockIdx.x;          // token 0..4095
  const int l = t & (L_ - 1);
  const int j = threadIdx.x & 15;    // 16 threads per head
  const int h = threadIdx.x >> 4;
  const int dd = (j & 7) * 4;
  float4 cv = *(const float4*)&cosT[l * 32 + dd];
  float4 sv = *(const float4*)&sinT[l * 32 + dd];
  const float sgn = (j < 8) ? -1.f : 1.f;
#pragma unroll
  for (int ic = 0; ic < 2; ++ic) {
    const float qsc = (ic == 0) ? 0.125f * 1.44269504088896341f : 1.f;
    ushort_t* base = qk + (size_t)t * 2048 + ic * DIM_ + h * HD_ + j * 4;
    ushort4 raw = *(const ushort4*)base;
    float x0 = b2f(raw.x), x1 = b2f(raw.y), x2 = b2f(raw.z), x3 = b2f(raw.w);
    float ss = x0 * x0 + x1 * x1 + x2 * x2 + x3 * x3;
    ss += __shfl_xor(ss, 1); ss += __shfl_xor(ss, 2);
    ss += __shfl_xor(ss, 4); ss += __shfl_xor(ss, 8);
    float inv = rsqrtf(ss * (1.f / 64.f) + 1e-6f);
    const float* scp = (ic == 0 ? qs : ks) + j * 4;
    float4 sc = *(const float4*)scp;
    x0 *= inv * sc.x; x1 *= inv * sc.y; x2 *= inv * sc.z; x3 *= inv * sc.w;
    float y0 = __shfl_xor(x0, 8), y1 = __shfl_xor(x1, 8);
    float y2 = __shfl_xor(x2, 8), y3 = __shfl_xor(x3, 8);
    ushort4 o;
    o.x = f2b((x0 * cv.x + sgn * y0 * sv.x) * qsc);
    o.y = f2b((x1 * cv.y + sgn * y1 * sv.y) * qsc);
    o.z = f2b((x2 * cv.z + sgn * y2 * sv.z) * qsc);
    o.w = f2b((x3 * cv.w + sgn * y3 * sv.w) * qsc);
    *(ushort4*)base = o;
  }
}

// ---------------- flash attention, 32x32 MFMA, joint half-tiles, K-split ----------------
// SPLIT=1: grid (L/128, H, B*2), half K range per block, bf16 partials + (m,l).
// Per 64-k tile: ONE 8-MFMA QK cluster (both 32-k half-tiles, C-init = -mrow),
// ONE joint max tree + ONE defer-branch + ONE cross-half shfl, exp2+cvt_pk,
// then a 12-MFMA PV cluster where the row-sum rides the matrix pipe via a
// ones-A MFMA (laccv; only [0] is ever rescaled/read -> no epilogue shfl).
// Register budget ~135 under launch_bounds(256,3).
template <int SPLIT>
__global__ __launch_bounds__(256, 3)
void flash_attn(const ushort_t* __restrict__ qk, const ushort_t* __restrict__ vt,
                ushort_t* __restrict__ O, ushort_t* __restrict__ Opart,
                float* __restrict__ Ml) {
  const int qt = blockIdx.x, h = blockIdx.y;
  const int b  = SPLIT ? (int)(blockIdx.z >> 1) : (int)blockIdx.z;
  const int ks = SPLIT ? (int)(blockIdx.z & 1) : 0;
  const int ktBeg = SPLIT ? ks * (L_ / 128) : 0;     // 16 tiles per split
  const int ktEnd = SPLIT ? ktBeg + (L_ / 128) : (L_ / 64);
  const int lane = threadIdx.x & 63, wid = threadIdx.x >> 6;
  const int lq = lane & 31;          // q (QK) / d' (PV A) / col index
  const int hi = lane >> 5;          // lane-half: k-slice half selector
  const int q0 = qt * 128;
  const size_t tok0 = (size_t)b * L_;
  const ushort_t* qb = qk + tok0 * 2048 + h * HD_;
  const ushort_t* kb = qb + DIM_;
  const ushort_t* vb = vt + ((size_t)b * DIM_ + h * HD_) * L_;

  __shared__ ushort_t Ks[2][4096];   // [kpos 64][d 64], 16B-chunk XOR swizzle
  __shared__ ushort_t Vs[2][4096];   // [d 64][kpos 64], same swizzle

  // staging: pointer-increment form.  row offsets j*8 keep the same swizzle
  // channel (j*8 ≡ 0 mod 8), so one sc per thread.
  const int srow0 = wid * 16 + (lane >> 3);
  const int sc    = (lane & 7) ^ (srow0 & 7);
  const ushort_t* kst = kb + (size_t)(ktBeg * 64 + srow0) * 2048 + sc * 8;
  const ushort_t* vst = vb + (size_t)srow0 * L_ + ktBeg * 64 + sc * 8;
  auto STAGE = [&](int bufi) {
    gload_lds16(kst,            &Ks[bufi][wid * 1024]);
    gload_lds16(kst + 8 * 2048, &Ks[bufi][wid * 1024 + 512]);
    gload_lds16(vst,            &Vs[bufi][wid * 1024]);
    gload_lds16(vst + 8 * L_,   &Vs[bufi][wid * 1024 + 512]);
    kst += 64 * 2048;
    vst += 64;
  };

  // Q fragments: B-operand of QK^T.  qf[s]: Q[q=lq][d = 16s + hi*8 + j]
  bf16x8 qf[4];
  {
    const ushort_t* gp = qb + (size_t)(q0 + wid * 32 + lq) * 2048;
#pragma unroll
    for (int s = 0; s < 4; ++s)
      qf[s] = *(const bf16x8*)(gp + s * 16 + hi * 8);
  }

  // ones A-operand: row-sum of P on the matrix pipe
  bf16x8 onesv;
#pragma unroll
  for (int i = 0; i < 8; ++i) onesv[i] = (__bf16)1.0f;

  // swizzled chunk byte-offsets (ushort units), shared by K d-slices and V
  // k-slices: chunk = (2*idx + hi) ^ (lq & 7)
  int chs[4];
#pragma unroll
  for (int s = 0; s < 4; ++s) chs[s] = ((2 * s + hi) ^ (lq & 7)) * 8;

  f32x16 oaccT[2] = {};              // [dtile] D[row=d'][col=q=lq]
  f32x16 laccv = {};                 // ones-MFMA row-sum; only [0] consumed
  float mrow = 0.f;                  // absolute running max (shifted trigger)

  STAGE(0);
  __syncthreads();

  auto TILE = [&](int bi, bool more) {
    if (more) STAGE(bi ^ 1);
    const ushort_t* kb0 = &Ks[bi][lq * 64];
    const ushort_t* vb0 = &Vs[bi][lq * 64];

    // QK both half-tiles, C-init = -mrow: st = S - mrow (shifted domain)
    f32x16 st0, st1;
#pragma unroll
    for (int i = 0; i < 16; ++i) { st0[i] = -mrow; st1[i] = -mrow; }
    __builtin_amdgcn_s_setprio(1);
#pragma unroll
    for (int s = 0; s < 4; ++s) {
      bf16x8 kf0 = *(const bf16x8*)(kb0 + chs[s]);
      bf16x8 kf1 = *(const bf16x8*)(kb0 + 2048 + chs[s]);
      st0 = __builtin_amdgcn_mfma_f32_32x32x16_bf16(kf0, qf[s], st0, 0, 0, 0);
      st1 = __builtin_amdgcn_mfma_f32_32x32x16_bf16(kf1, qf[s], st1, 0, 0, 0);
    }
    __builtin_amdgcn_s_setprio(0);

    // joint shifted max over 32 values (max3 tree) + cross-half
    float a0 = fmax3(st0[0],  st0[1],  st0[2]);
    float a1 = fmax3(st0[3],  st0[4],  st0[5]);
    float a2 = fmax3(st0[6],  st0[7],  st0[8]);
    float a3 = fmax3(st0[9],  st0[10], st0[11]);
    float a4 = fmax3(st0[12], st0[13], st0[14]);
    float a5 = fmax3(st0[15], st1[0],  st1[1]);
    float a6 = fmax3(st1[2],  st1[3],  st1[4]);
    float a7 = fmax3(st1[5],  st1[6],  st1[7]);
    float a8 = fmax3(st1[8],  st1[9],  st1[10]);
    float a9 = fmax3(st1[11], st1[12], st1[13]);
    float aa = fmaxf(st1[14], st1[15]);
    float c0 = fmax3(a0, a1, a2);
    float c1 = fmax3(a3, a4, a5);
    float c2 = fmax3(a6, a7, a8);
    float c3 = fmax3(a9, aa, c0);
    float pm = fmax3(c1, c2, c3);
    pm = fmaxf(pm, __shfl_xor(pm, 32));

    // defer-max: rescale only when max grew by >8 over mrow (log2 domain;
    // P then bounded by 2^8, f32 accum has ample headroom)
    if (__any(pm > 8.f)) {
      float d = fmaxf(pm, 0.f);
      float alpha = __builtin_amdgcn_exp2f(-d);
      mrow += d;
      laccv[0] *= alpha;             // only reg 0 is ever consumed
#pragma unroll
      for (int dt = 0; dt < 2; ++dt)
#pragma unroll
        for (int r = 0; r < 16; ++r) oaccT[dt][r] *= alpha;
#pragma unroll
      for (int i = 0; i < 16; ++i) { st0[i] -= d; st1[i] -= d; }
    }

    // P = exp2(st), packed bf16 pairs
    unsigned pk0[8], pk1[8];
#pragma unroll
    for (int p = 0; p < 8; ++p) {
      float e0 = __builtin_amdgcn_exp2f(st0[2 * p]);
      float e1 = __builtin_amdgcn_exp2f(st0[2 * p + 1]);
      pk0[p] = (unsigned)f2b(e0) | ((unsigned)f2b(e1) << 16);
      float f0 = __builtin_amdgcn_exp2f(st1[2 * p]);
      float f1 = __builtin_amdgcn_exp2f(st1[2 * p + 1]);
      pk1[p] = (unsigned)f2b(f0) | ((unsigned)f2b(f1) << 16);
    }

    // PV: redistribute P via permlane32_swap into B-fragments;
    // oaccT[dt] += mfma(V^T-frag, P-frag); laccv += mfma(ones, P-frag)
    __builtin_amdgcn_s_setprio(1);
#pragma unroll
    for (int t = 0; t < 2; ++t)
#pragma unroll
      for (int blk = 0; blk < 2; ++blk) {
        unsigned w0 = (t == 0) ? pk0[4 * blk + 0] : pk1[4 * blk + 0];
        unsigned w1 = (t == 0) ? pk0[4 * blk + 1] : pk1[4 * blk + 1];
        unsigned w2 = (t == 0) ? pk0[4 * blk + 2] : pk1[4 * blk + 2];
        unsigned w3 = (t == 0) ? pk0[4 * blk + 3] : pk1[4 * blk + 3];
        plswap(w0, w2);   // -> {j0j1, j4j5}
        plswap(w1, w3);   // -> {j2j3, j6j7}
        uint4 bw; bw.x = w0; bw.y = w1; bw.z = w2; bw.w = w3;
        bf16x8 pf = __builtin_bit_cast(bf16x8, bw);
        const int sg = 2 * t + blk;
        laccv = __builtin_amdgcn_mfma_f32_32x32x16_bf16(onesv, pf, laccv, 0, 0, 0);
#pragma unroll
        for (int dt = 0; dt < 2; ++dt) {
          bf16x8 vf = *(const bf16x8*)(vb0 + dt * 2048 + chs[sg]);
          oaccT[dt] = __builtin_amdgcn_mfma_f32_32x32x16_bf16(vf, pf,
                                                              oaccT[dt], 0, 0, 0);
        }
      }
    __builtin_amdgcn_s_setprio(0);

    __syncthreads();   // drains vmcnt: stage(next) complete; buffers safe
  };

  const int NT = ktEnd - ktBeg;      // 16 (split) or 32 (single), even
  for (int it = 0; it < NT; it += 2) {
    TILE(0, it + 1 < NT);
    TILE(1, it + 2 < NT);
  }

  // epilogue: lane-local (q = lq); laccv[0] = full row sum (ones-MFMA spans
  // all 64 lanes' P fragments -> both halves included, no shfl)
  const float lrow = laccv[0];
  const float linv = 1.f / lrow;
  const int tok = (int)tok0 + q0 + wid * 32 + lq;
  ushort_t* obp = (SPLIT ? Opart + (size_t)ks * M_ * DIM_ : O)
                  + (size_t)tok * DIM_ + h * HD_;
#pragma unroll
  for (int dt = 0; dt < 2; ++dt)
#pragma unroll
    for (int g4 = 0; g4 < 4; ++g4) {
      int d0 = dt * 32 + g4 * 8 + hi * 4;
      ushort4 o4;
      o4.x = f2b(oaccT[dt][4 * g4 + 0] * linv);
      o4.y = f2b(oaccT[dt][4 * g4 + 1] * linv);
      o4.z = f2b(oaccT[dt][4 * g4 + 2] * linv);
      o4.w = f2b(oaccT[dt][4 * g4 + 3] * linv);
      *(ushort4*)(obp + d0) = o4;
    }
  if (SPLIT && hi == 0) {
    float2 ml; ml.x = mrow; ml.y = lrow;
    *(float2*)&Ml[(((size_t)ks * M_ + tok) * H_ + h) * 2] = ml;
  }
}

// ---------------- combine two K-split partials (bf16) -> bf16 O ----------------
// O = w0*O0 + w1*O1, w_i = l_i*2^(m_i-M) / sum  (partials are normalized)
__global__ __launch_bounds__(256)
void attn_combine(const ushort_t* __restrict__ Opart, const float* __restrict__ Ml,
                  ushort_t* __restrict__ O) {
  int idx = blockIdx.x * 256 + threadIdx.x;   // 524288 threads, 8 bf16 each
  int c   = idx & 127;                        // chunk-of-8 within row
  int tok = idx >> 7;
  int h   = c >> 3;
  float2 ml0 = *(const float2*)&Ml[(((size_t)0 * M_ + tok) * H_ + h) * 2];
  float2 ml1 = *(const float2*)&Ml[(((size_t)1 * M_ + tok) * H_ + h) * 2];
  float mM = fmaxf(ml0.x, ml1.x);
  float w0 = ml0.y * __builtin_amdgcn_exp2f(ml0.x - mM);
  float w1 = ml1.y * __builtin_amdgcn_exp2f(ml1.x - mM);
  float inv = 1.f / (w0 + w1);
  w0 *= inv; w1 *= inv;
  size_t off = (size_t)tok * DIM_ + c * 8;
  uint4 a = *(const uint4*)&Opart[off];
  uint4 d = *(const uint4*)&Opart[(size_t)M_ * DIM_ + off];
  auto mix = [&](unsigned ua, unsigned ud) -> unsigned {
    float a0 = b2f((unsigned short)(ua & 0xffff)), a1 = b2f((unsigned short)(ua >> 16));
    float d0 = b2f((unsigned short)(ud & 0xffff)), d1 = b2f((unsigned short)(ud >> 16));
    unsigned r0 = f2b(a0 * w0 + d0 * w1), r1 = f2b(a1 * w0 + d1 * w1);
    return r0 | (r1 << 16);
  };
  uint4 o;
  o.x = mix(a.x, d.x); o.y = mix(a.y, d.y);
  o.z = mix(a.z, d.z); o.w = mix(a.w, d.w);
  *(uint4*)&O[off] = o;
}

// ---------------- launch ----------------
extern "C" void kernel_launch(void* const* d_in, const int* in_sizes, int n_in,
                              void* d_out, int out_size, void* d_ws, size_t ws_size,
                              hipStream_t stream) {
  const float* x     = (const float*)d_in[0];
  const float* Wqkv  = (const float*)d_in[1];
  const float* qs    = (const float*)d_in[2];
  const float* ks    = (const float*)d_in[3];
  const float* Wproj = (const float*)d_in[4];
  const float* bproj = (const float*)d_in[5];
  float* out = (float*)d_out;

  char* ws = (char*)d_ws;
  ushort_t* xb     = (ushort_t*)(ws);                                  // 8 MB
  ushort_t* WqkvT  = (ushort_t*)(ws + (size_t)(8u << 20));             // 6 MB
  ushort_t* WprojT = (ushort_t*)(ws + (size_t)(14u << 20));            // 2 MB
  ushort_t* qkb    = (ushort_t*)(ws + (size_t)(16u << 20));            // 16 MB [4096][2048]
  ushort_t* vtb    = (ushort_t*)(ws + (size_t)(32u << 20));            // 8 MB  [2][1024][2048]
  float*    cosT   = (float*)(ws + (size_t)(40u << 20));               // 256 KB
  float*    sinT   = (float*)(ws + (size_t)(40u << 20) + (256u << 10));// 256 KB
  ushort_t* ob     = (ushort_t*)(ws + (size_t)(41u << 20));            // 8 MB
  ushort_t* Opart  = (ushort_t*)(ws + (size_t)(49u << 20));            // 16 MB [2][4096][1024] bf16
  float*    Ml     = (float*)(ws + (size_t)(65u << 20));               // 1 MB  [2][4096][16][2] f32

  preproc<<<5376, 256, 0, stream>>>(x, xb, Wqkv, WqkvT, Wproj, WprojT,
                                    cosT, sinT);
  gemm_bt<0><<<dim3(24, 32), 256, 0, stream>>>(xb, WqkvT, qkb, vtb, nullptr,
                                               M_, N3_, DIM_, 2048);
  rmsrope<<<4096, 256, 0, stream>>>(qkb, qs, ks, cosT, sinT);
  if (ws_size >= ((size_t)66u << 20)) {
    flash_attn<1><<<dim3(16, 16, 4), 256, 0, stream>>>(qkb, vtb, nullptr,
                                                       Opart, Ml);
    attn_combine<<<2048, 256, 0, stream>>>(Opart, Ml, ob);
  } else {
    flash_attn<0><<<dim3(16, 16, 2), 256, 0, stream>>>(qkb, vtb, ob,
                                                       nullptr, nullptr);
  }
  gemm_bt<1><<<dim3(8, 32), 256, 0, stream>>>(ob, WprojT, out, nullptr, bproj,
                                              M_, DIM_, DIM_, DIM_);
}

// Round 7
// 140.195 us; speedup vs baseline: 1.1399x; 1.0404x over previous
//
#include <hip/hip_runtime.h>
#include <hip/hip_bf16.h>
#include <cstdint>

#define B_   2
#define L_   2048
#define DIM_ 1024
#define H_   16
#define HD_  64
#define M_   (B_ * L_)    // 4096
#define N3_  (3 * DIM_)   // 3072

typedef unsigned short ushort_t;
typedef __bf16 bf16x8 __attribute__((ext_vector_type(8)));
typedef float  f32x4  __attribute__((ext_vector_type(4)));
typedef float  f32x16 __attribute__((ext_vector_type(16)));
typedef unsigned u32x2_t __attribute__((ext_vector_type(2)));

// native cast -> compiler emits v_cvt_pk_bf16_f32 for adjacent pairs (RTNE)
__device__ __forceinline__ unsigned short f2b(float f) {
  return __builtin_bit_cast(unsigned short, (__bf16)f);
}
__device__ __forceinline__ float b2f(unsigned short s) {
  unsigned u = ((unsigned)s) << 16;
  return __builtin_bit_cast(float, u);
}
__device__ __forceinline__ float fmax3(float a, float b, float c) {
  return fmaxf(fmaxf(a, b), c);   // fuses to v_max3_f32
}

// {a,b} -> a' = [a_lo | b_lo], b' = [a_hi | b_hi]  (lane halves)
__device__ __forceinline__ void plswap(unsigned &a, unsigned &b) {
#if defined(__has_builtin) && __has_builtin(__builtin_amdgcn_permlane32_swap)
  u32x2_t r = __builtin_amdgcn_permlane32_swap(a, b, false, false);
  a = r[0]; b = r[1];
#else
  unsigned sa = (unsigned)__shfl_xor((int)a, 32);
  unsigned sb = (unsigned)__shfl_xor((int)b, 32);
  bool hi = (threadIdx.x & 32) != 0;
  unsigned na = hi ? sb : a;
  unsigned nb = hi ? b : sa;
  a = na; b = nb;
#endif
}

typedef const __attribute__((address_space(1))) void* as1cp;
typedef __attribute__((address_space(3))) void* as3p;
__device__ __forceinline__ void gload_lds16(const void* g, void* l) {
  __builtin_amdgcn_global_load_lds((as1cp)g, (as3p)l, 16, 0, 0);
}

// ---------------- fused preprocessing ----------------
// blk [0,4096):      f32 -> bf16 convert of x (1M float4)
// blk [4096,4864):   Wqkv  f32 [1024][3072] -> bf16 [3072][1024] transpose
// blk [4864,5120):   Wproj f32 [1024][1024] -> bf16 [1024][1024] transpose
// blk [5120,5376):   rope cos/sin table [2048][32]
__global__ __launch_bounds__(256)
void preproc(const float* __restrict__ x, ushort_t* __restrict__ xb,
             const float* __restrict__ Wqkv, ushort_t* __restrict__ WqkvT,
             const float* __restrict__ Wproj, ushort_t* __restrict__ WprojT,
             float* __restrict__ cosT, float* __restrict__ sinT) {
  __shared__ float tile[64][65];
  const int blk = blockIdx.x;
  const int t = threadIdx.x;
  if (blk < 4096) {
    int i = blk * 256 + t;
    float4 v = *(const float4*)&x[(size_t)i * 4];
    ushort4 o;
    o.x = f2b(v.x); o.y = f2b(v.y); o.z = f2b(v.z); o.w = f2b(v.w);
    *(ushort4*)&xb[(size_t)i * 4] = o;
  } else if (blk < 5120) {
    const float* in;
    ushort_t* out;
    int C, bi;
    if (blk < 4864) { in = Wqkv; out = WqkvT; C = 3072; bi = blk - 4096; }
    else            { in = Wproj; out = WprojT; C = 1024; bi = blk - 4864; }
    const int nbx = C >> 6;
    const int bx = bi % nbx, by = bi / nbx;
    const int r0 = by * 64, c0 = bx * 64;
    const int R = 1024;
#pragma unroll
    for (int p = 0; p < 4; ++p) {
      int r = (t >> 4) + p * 16;
      int c = (t & 15) * 4;
      float4 v = *(const float4*)&in[(size_t)(r0 + r) * C + (c0 + c)];
      tile[r][c + 0] = v.x; tile[r][c + 1] = v.y;
      tile[r][c + 2] = v.z; tile[r][c + 3] = v.w;
    }
    __syncthreads();
#pragma unroll
    for (int p = 0; p < 4; ++p) {
      int cc = (t >> 4) + p * 16;
      int r  = (t & 15) * 4;
      ushort4 o;
      o.x = f2b(tile[r + 0][cc]); o.y = f2b(tile[r + 1][cc]);
      o.z = f2b(tile[r + 2][cc]); o.w = f2b(tile[r + 3][cc]);
      *(ushort4*)&out[(size_t)(c0 + cc) * R + (r0 + r)] = o;
    }
  } else {
    int idx = (blk - 5120) * 256 + t;   // 65536 = 2048*32
    int l = idx >> 5, d = idx & 31;
    float inv_freq = expf(-((float)(2 * d) / 64.f) * logf(10000.f));
    float ang = (float)l * inv_freq;
    cosT[idx] = cosf(ang);
    sinT[idx] = sinf(ang);
  }
}

// ---------------- GEMM: A[M][K] bf16 @ BT[N][K] bf16 ----------------
// 128x128 tile, BK=32, 4 waves (2x2), 16x16x32 MFMA, global_load_lds staging.
// MODE 0: QKV gemm.  q,k cols [0,2048): fused per-head RMSNorm + RoPE applied
//         in the epilogue (wave's 64-col slice = exactly one head; q/k split
//         at col 1024 is block-uniform), then bf16 -> Cqk[row][ldc].  Q cols
//         additionally prescaled by 0.125*log2(e).  V cols [2048,3072)
//         transposed to vt[b][d][l].
// MODE 1: f32 out + bias.
template <int MODE>
__global__ __launch_bounds__(256)
void gemm_bt(const ushort_t* __restrict__ A, const ushort_t* __restrict__ BT,
             void* __restrict__ Cout, ushort_t* __restrict__ vtout,
             const float* __restrict__ bias, int M, int N, int K, int ldc,
             const float* __restrict__ qsc_, const float* __restrict__ ksc_,
             const float* __restrict__ cosT, const float* __restrict__ sinT) {
  __shared__ ushort_t As[128 * 32];
  __shared__ ushort_t Bs[128 * 32];
  const int lane = threadIdx.x & 63;
  const int wid  = threadIdx.x >> 6;
  const int wm = wid >> 1, wn = wid & 1;
  const int m0 = blockIdx.y * 128, n0 = blockIdx.x * 128;
  const int ro = lane & 15, kg = lane >> 4;

  f32x4 acc[4][4] = {};

  for (int k0 = 0; k0 < K; k0 += 32) {
    const int cb = wid * 128;
#pragma unroll
    for (int j = 0; j < 2; ++j) {
      int c = cb + j * 64 + lane;
      gload_lds16(A + (size_t)(m0 + (c >> 2)) * K + k0 + (c & 3) * 8,
                  &As[(cb + j * 64) * 8]);
    }
#pragma unroll
    for (int j = 0; j < 2; ++j) {
      int c = cb + j * 64 + lane;
      gload_lds16(BT + (size_t)(n0 + (c >> 2)) * K + k0 + (c & 3) * 8,
                  &Bs[(cb + j * 64) * 8]);
    }
    __syncthreads();
    bf16x8 af[4], bfr[4];
#pragma unroll
    for (int i = 0; i < 4; ++i)
      af[i] = *(const bf16x8*)&As[(wm * 64 + i * 16 + ro) * 32 + kg * 8];
#pragma unroll
    for (int i = 0; i < 4; ++i)
      bfr[i] = *(const bf16x8*)&Bs[(wn * 64 + i * 16 + ro) * 32 + kg * 8];
#pragma unroll
    for (int i = 0; i < 4; ++i)
#pragma unroll
      for (int j = 0; j < 4; ++j)
        acc[i][j] = __builtin_amdgcn_mfma_f32_16x16x32_bf16(af[i], bfr[j],
                                                            acc[i][j], 0, 0, 0);
    __syncthreads();
  }

  if (MODE == 0) {
    if (n0 < 2048) {
      // fused RMSNorm + RoPE.  d = j*16 + ro within this wave's head.
      const int ic = (n0 >= 1024);             // 0 = q, 1 = k (block-uniform)
      const float* scp = ic ? ksc_ : qsc_;
      const float qsc = ic ? 1.f : 0.125f * 1.44269504088896341f;
      float sc[4];
#pragma unroll
      for (int j = 0; j < 4; ++j) sc[j] = scp[j * 16 + ro];
#pragma unroll
      for (int i = 0; i < 4; ++i)
#pragma unroll
        for (int r = 0; r < 4; ++r) {
          int row = m0 + wm * 64 + i * 16 + kg * 4 + r;
          int l = row & (L_ - 1);
          float x0 = acc[i][0][r], x1 = acc[i][1][r];
          float x2 = acc[i][2][r], x3 = acc[i][3][r];
          float ss = x0 * x0 + x1 * x1 + x2 * x2 + x3 * x3;
          ss += __shfl_xor(ss, 1); ss += __shfl_xor(ss, 2);
          ss += __shfl_xor(ss, 4); ss += __shfl_xor(ss, 8);
          float inv = rsqrtf(ss * (1.f / 64.f) + 1e-6f);
          x0 *= inv * sc[0]; x1 *= inv * sc[1];
          x2 *= inv * sc[2]; x3 *= inv * sc[3];
          float cv0 = cosT[l * 32 + ro],      sv0 = sinT[l * 32 + ro];
          float cv1 = cosT[l * 32 + 16 + ro], sv1 = sinT[l * 32 + 16 + ro];
          float o0 = (x0 * cv0 - x2 * sv0) * qsc;
          float o1 = (x1 * cv1 - x3 * sv1) * qsc;
          float o2 = (x2 * cv0 + x0 * sv0) * qsc;
          float o3 = (x3 * cv1 + x1 * sv1) * qsc;
          ushort_t* cp = (ushort_t*)Cout + (size_t)row * ldc + n0 + wn * 64 + ro;
          cp[0]  = f2b(o0);
          cp[16] = f2b(o1);
          cp[32] = f2b(o2);
          cp[48] = f2b(o3);
        }
    } else {
      // V columns -> vt[b][dg][l], 4 consecutive l per lane packed
#pragma unroll
      for (int i = 0; i < 4; ++i) {
        int rowb = m0 + wm * 64 + i * 16 + kg * 4;
        int bb = rowb >> 11, l = rowb & (L_ - 1);
#pragma unroll
        for (int j = 0; j < 4; ++j) {
          int dg = (n0 - 2048) + wn * 64 + j * 16 + ro;
          ushort4 o;
          o.x = f2b(acc[i][j][0]); o.y = f2b(acc[i][j][1]);
          o.z = f2b(acc[i][j][2]); o.w = f2b(acc[i][j][3]);
          *(ushort4*)&vtout[((size_t)bb * DIM_ + dg) * L_ + l] = o;
        }
      }
    }
  } else {
#pragma unroll
    for (int i = 0; i < 4; ++i)
#pragma unroll
      for (int r = 0; r < 4; ++r) {
        int row = m0 + wm * 64 + i * 16 + kg * 4 + r;
#pragma unroll
        for (int j = 0; j < 4; ++j) {
          int col = n0 + wn * 64 + j * 16 + ro;
          ((float*)Cout)[(size_t)row * ldc + col] = acc[i][j][r] + bias[col];
        }
      }
  }
}

// ---------------- flash attention, 32x32 MFMA, joint half-tiles, K-split ----------------
// SPLIT=1: grid (L/128, H, B*2), half K range per block, bf16 partials + (m,l).
// Per 64-k tile: ONE 8-MFMA QK cluster (both 32-k half-tiles, C-init = -mrow),
// ONE joint max tree + ONE defer-branch + ONE cross-half shfl, exp2+cvt_pk,
// then a 12-MFMA PV cluster where the row-sum rides the matrix pipe via a
// ones-A MFMA (laccv; only [0] is ever rescaled/read -> no epilogue shfl).
template <int SPLIT>
__global__ __launch_bounds__(256, 3)
void flash_attn(const ushort_t* __restrict__ qk, const ushort_t* __restrict__ vt,
                ushort_t* __restrict__ O, ushort_t* __restrict__ Opart,
                float* __restrict__ Ml) {
  const int qt = blockIdx.x, h = blockIdx.y;
  const int b  = SPLIT ? (int)(blockIdx.z >> 1) : (int)blockIdx.z;
  const int ks = SPLIT ? (int)(blockIdx.z & 1) : 0;
  const int ktBeg = SPLIT ? ks * (L_ / 128) : 0;     // 16 tiles per split
  const int ktEnd = SPLIT ? ktBeg + (L_ / 128) : (L_ / 64);
  const int lane = threadIdx.x & 63, wid = threadIdx.x >> 6;
  const int lq = lane & 31;          // q (QK) / d' (PV A) / col index
  const int hi = lane >> 5;          // lane-half: k-slice half selector
  const int q0 = qt * 128;
  const size_t tok0 = (size_t)b * L_;
  const ushort_t* qb = qk + tok0 * 2048 + h * HD_;
  const ushort_t* kb = qb + DIM_;
  const ushort_t* vb = vt + ((size_t)b * DIM_ + h * HD_) * L_;

  __shared__ ushort_t Ks[2][4096];   // [kpos 64][d 64], 16B-chunk XOR swizzle
  __shared__ ushort_t Vs[2][4096];   // [d 64][kpos 64], same swizzle

  // staging: pointer-increment form.  row offsets j*8 keep the same swizzle
  // channel (j*8 ≡ 0 mod 8), so one sc per thread.
  const int srow0 = wid * 16 + (lane >> 3);
  const int sc    = (lane & 7) ^ (srow0 & 7);
  const ushort_t* kst = kb + (size_t)(ktBeg * 64 + srow0) * 2048 + sc * 8;
  const ushort_t* vst = vb + (size_t)srow0 * L_ + ktBeg * 64 + sc * 8;
  auto STAGE = [&](int bufi) {
    gload_lds16(kst,            &Ks[bufi][wid * 1024]);
    gload_lds16(kst + 8 * 2048, &Ks[bufi][wid * 1024 + 512]);
    gload_lds16(vst,            &Vs[bufi][wid * 1024]);
    gload_lds16(vst + 8 * L_,   &Vs[bufi][wid * 1024 + 512]);
    kst += 64 * 2048;
    vst += 64;
  };

  // Q fragments: B-operand of QK^T.  qf[s]: Q[q=lq][d = 16s + hi*8 + j]
  bf16x8 qf[4];
  {
    const ushort_t* gp = qb + (size_t)(q0 + wid * 32 + lq) * 2048;
#pragma unroll
    for (int s = 0; s < 4; ++s)
      qf[s] = *(const bf16x8*)(gp + s * 16 + hi * 8);
  }

  // ones A-operand: row-sum of P on the matrix pipe
  bf16x8 onesv;
#pragma unroll
  for (int i = 0; i < 8; ++i) onesv[i] = (__bf16)1.0f;

  // swizzled chunk byte-offsets (ushort units), shared by K d-slices and V
  // k-slices: chunk = (2*idx + hi) ^ (lq & 7)
  int chs[4];
#pragma unroll
  for (int s = 0; s < 4; ++s) chs[s] = ((2 * s + hi) ^ (lq & 7)) * 8;

  f32x16 oaccT[2] = {};              // [dtile] D[row=d'][col=q=lq]
  f32x16 laccv = {};                 // ones-MFMA row-sum; only [0] consumed
  float mrow = 0.f;                  // absolute running max (shifted trigger)

  STAGE(0);
  __syncthreads();

  auto TILE = [&](int bi, bool more) {
    if (more) STAGE(bi ^ 1);
    const ushort_t* kb0 = &Ks[bi][lq * 64];
    const ushort_t* vb0 = &Vs[bi][lq * 64];

    // QK both half-tiles, C-init = -mrow: st = S - mrow (shifted domain)
    f32x16 st0, st1;
#pragma unroll
    for (int i = 0; i < 16; ++i) { st0[i] = -mrow; st1[i] = -mrow; }
    __builtin_amdgcn_s_setprio(1);
#pragma unroll
    for (int s = 0; s < 4; ++s) {
      bf16x8 kf0 = *(const bf16x8*)(kb0 + chs[s]);
      bf16x8 kf1 = *(const bf16x8*)(kb0 + 2048 + chs[s]);
      st0 = __builtin_amdgcn_mfma_f32_32x32x16_bf16(kf0, qf[s], st0, 0, 0, 0);
      st1 = __builtin_amdgcn_mfma_f32_32x32x16_bf16(kf1, qf[s], st1, 0, 0, 0);
    }
    __builtin_amdgcn_s_setprio(0);

    // joint shifted max over 32 values (max3 tree) + cross-half
    float a0 = fmax3(st0[0],  st0[1],  st0[2]);
    float a1 = fmax3(st0[3],  st0[4],  st0[5]);
    float a2 = fmax3(st0[6],  st0[7],  st0[8]);
    float a3 = fmax3(st0[9],  st0[10], st0[11]);
    float a4 = fmax3(st0[12], st0[13], st0[14]);
    float a5 = fmax3(st0[15], st1[0],  st1[1]);
    float a6 = fmax3(st1[2],  st1[3],  st1[4]);
    float a7 = fmax3(st1[5],  st1[6],  st1[7]);
    float a8 = fmax3(st1[8],  st1[9],  st1[10]);
    float a9 = fmax3(st1[11], st1[12], st1[13]);
    float aa = fmaxf(st1[14], st1[15]);
    float c0 = fmax3(a0, a1, a2);
    float c1 = fmax3(a3, a4, a5);
    float c2 = fmax3(a6, a7, a8);
    float c3 = fmax3(a9, aa, c0);
    float pm = fmax3(c1, c2, c3);
    pm = fmaxf(pm, __shfl_xor(pm, 32));

    // defer-max: rescale only when max grew by >8 over mrow (log2 domain;
    // P then bounded by 2^8, f32 accum has ample headroom)
    if (__any(pm > 8.f)) {
      float d = fmaxf(pm, 0.f);
      float alpha = __builtin_amdgcn_exp2f(-d);
      mrow += d;
      laccv[0] *= alpha;             // only reg 0 is ever consumed
#pragma unroll
      for (int dt = 0; dt < 2; ++dt)
#pragma unroll
        for (int r = 0; r < 16; ++r) oaccT[dt][r] *= alpha;
#pragma unroll
      for (int i = 0; i < 16; ++i) { st0[i] -= d; st1[i] -= d; }
    }

    // P = exp2(st), packed bf16 pairs
    unsigned pk0[8], pk1[8];
#pragma unroll
    for (int p = 0; p < 8; ++p) {
      float e0 = __builtin_amdgcn_exp2f(st0[2 * p]);
      float e1 = __builtin_amdgcn_exp2f(st0[2 * p + 1]);
      pk0[p] = (unsigned)f2b(e0) | ((unsigned)f2b(e1) << 16);
      float f0 = __builtin_amdgcn_exp2f(st1[2 * p]);
      float f1 = __builtin_amdgcn_exp2f(st1[2 * p + 1]);
      pk1[p] = (unsigned)f2b(f0) | ((unsigned)f2b(f1) << 16);
    }

    // PV: redistribute P via permlane32_swap into B-fragments;
    // oaccT[dt] += mfma(V^T-frag, P-frag); laccv += mfma(ones, P-frag)
    __builtin_amdgcn_s_setprio(1);
#pragma unroll
    for (int t = 0; t < 2; ++t)
#pragma unroll
      for (int blk = 0; blk < 2; ++blk) {
        unsigned w0 = (t == 0) ? pk0[4 * blk + 0] : pk1[4 * blk + 0];
        unsigned w1 = (t == 0) ? pk0[4 * blk + 1] : pk1[4 * blk + 1];
        unsigned w2 = (t == 0) ? pk0[4 * blk + 2] : pk1[4 * blk + 2];
        unsigned w3 = (t == 0) ? pk0[4 * blk + 3] : pk1[4 * blk + 3];
        plswap(w0, w2);   // -> {j0j1, j4j5}
        plswap(w1, w3);   // -> {j2j3, j6j7}
        uint4 bw; bw.x = w0; bw.y = w1; bw.z = w2; bw.w = w3;
        bf16x8 pf = __builtin_bit_cast(bf16x8, bw);
        const int sg = 2 * t + blk;
        laccv = __builtin_amdgcn_mfma_f32_32x32x16_bf16(onesv, pf, laccv, 0, 0, 0);
#pragma unroll
        for (int dt = 0; dt < 2; ++dt) {
          bf16x8 vf = *(const bf16x8*)(vb0 + dt * 2048 + chs[sg]);
          oaccT[dt] = __builtin_amdgcn_mfma_f32_32x32x16_bf16(vf, pf,
                                                              oaccT[dt], 0, 0, 0);
        }
      }
    __builtin_amdgcn_s_setprio(0);

    __syncthreads();   // drains vmcnt: stage(next) complete; buffers safe
  };

  const int NT = ktEnd - ktBeg;      // 16 (split) or 32 (single), even
  for (int it = 0; it < NT; it += 2) {
    TILE(0, it + 1 < NT);
    TILE(1, it + 2 < NT);
  }

  // epilogue: lane-local (q = lq); laccv[0] = full row sum (ones-MFMA spans
  // all 64 lanes' P fragments -> both halves included, no shfl)
  const float lrow = laccv[0];
  const float linv = 1.f / lrow;
  const int tok = (int)tok0 + q0 + wid * 32 + lq;
  ushort_t* obp = (SPLIT ? Opart + (size_t)ks * M_ * DIM_ : O)
                  + (size_t)tok * DIM_ + h * HD_;
#pragma unroll
  for (int dt = 0; dt < 2; ++dt)
#pragma unroll
    for (int g4 = 0; g4 < 4; ++g4) {
      int d0 = dt * 32 + g4 * 8 + hi * 4;
      ushort4 o4;
      o4.x = f2b(oaccT[dt][4 * g4 + 0] * linv);
      o4.y = f2b(oaccT[dt][4 * g4 + 1] * linv);
      o4.z = f2b(oaccT[dt][4 * g4 + 2] * linv);
      o4.w = f2b(oaccT[dt][4 * g4 + 3] * linv);
      *(ushort4*)(obp + d0) = o4;
    }
  if (SPLIT && hi == 0) {
    float2 ml; ml.x = mrow; ml.y = lrow;
    *(float2*)&Ml[(((size_t)ks * M_ + tok) * H_ + h) * 2] = ml;
  }
}

// ---------------- combine two K-split partials (bf16) -> bf16 O ----------------
// O = w0*O0 + w1*O1, w_i = l_i*2^(m_i-M) / sum  (partials are normalized)
__global__ __launch_bounds__(256)
void attn_combine(const ushort_t* __restrict__ Opart, const float* __restrict__ Ml,
                  ushort_t* __restrict__ O) {
  int idx = blockIdx.x * 256 + threadIdx.x;   // 524288 threads, 8 bf16 each
  int c   = idx & 127;                        // chunk-of-8 within row
  int tok = idx >> 7;
  int h   = c >> 3;
  float2 ml0 = *(const float2*)&Ml[(((size_t)0 * M_ + tok) * H_ + h) * 2];
  float2 ml1 = *(const float2*)&Ml[(((size_t)1 * M_ + tok) * H_ + h) * 2];
  float mM = fmaxf(ml0.x, ml1.x);
  float w0 = ml0.y * __builtin_amdgcn_exp2f(ml0.x - mM);
  float w1 = ml1.y * __builtin_amdgcn_exp2f(ml1.x - mM);
  float inv = 1.f / (w0 + w1);
  w0 *= inv; w1 *= inv;
  size_t off = (size_t)tok * DIM_ + c * 8;
  uint4 a = *(const uint4*)&Opart[off];
  uint4 d = *(const uint4*)&Opart[(size_t)M_ * DIM_ + off];
  auto mix = [&](unsigned ua, unsigned ud) -> unsigned {
    float a0 = b2f((unsigned short)(ua & 0xffff)), a1 = b2f((unsigned short)(ua >> 16));
    float d0 = b2f((unsigned short)(ud & 0xffff)), d1 = b2f((unsigned short)(ud >> 16));
    unsigned r0 = f2b(a0 * w0 + d0 * w1), r1 = f2b(a1 * w0 + d1 * w1);
    return r0 | (r1 << 16);
  };
  uint4 o;
  o.x = mix(a.x, d.x); o.y = mix(a.y, d.y);
  o.z = mix(a.z, d.z); o.w = mix(a.w, d.w);
  *(uint4*)&O[off] = o;
}

// ---------------- launch ----------------
extern "C" void kernel_launch(void* const* d_in, const int* in_sizes, int n_in,
                              void* d_out, int out_size, void* d_ws, size_t ws_size,
                              hipStream_t stream) {
  const float* x     = (const float*)d_in[0];
  const float* Wqkv  = (const float*)d_in[1];
  const float* qs    = (const float*)d_in[2];
  const float* ks    = (const float*)d_in[3];
  const float* Wproj = (const float*)d_in[4];
  const float* bproj = (const float*)d_in[5];
  float* out = (float*)d_out;

  char* ws = (char*)d_ws;
  ushort_t* xb     = (ushort_t*)(ws);                                  // 8 MB
  ushort_t* WqkvT  = (ushort_t*)(ws + (size_t)(8u << 20));             // 6 MB
  ushort_t* WprojT = (ushort_t*)(ws + (size_t)(14u << 20));            // 2 MB
  ushort_t* qkb    = (ushort_t*)(ws + (size_t)(16u << 20));            // 16 MB [4096][2048]
  ushort_t* vtb    = (ushort_t*)(ws + (size_t)(32u << 20));            // 8 MB  [2][1024][2048]
  float*    cosT   = (float*)(ws + (size_t)(40u << 20));               // 256 KB
  float*    sinT   = (float*)(ws + (size_t)(40u << 20) + (256u << 10));// 256 KB
  ushort_t* ob     = (ushort_t*)(ws + (size_t)(41u << 20));            // 8 MB
  ushort_t* Opart  = (ushort_t*)(ws + (size_t)(49u << 20));            // 16 MB [2][4096][1024] bf16
  float*    Ml     = (float*)(ws + (size_t)(65u << 20));               // 1 MB  [2][4096][16][2] f32

  preproc<<<5376, 256, 0, stream>>>(x, xb, Wqkv, WqkvT, Wproj, WprojT,
                                    cosT, sinT);
  gemm_bt<0><<<dim3(24, 32), 256, 0, stream>>>(xb, WqkvT, qkb, vtb, nullptr,
                                               M_, N3_, DIM_, 2048,
                                               qs, ks, cosT, sinT);
  if (ws_size >= ((size_t)66u << 20)) {
    flash_attn<1><<<dim3(16, 16, 4), 256, 0, stream>>>(qkb, vtb, nullptr,
                                                       Opart, Ml);
    attn_combine<<<2048, 256, 0, stream>>>(Opart, Ml, ob);
  } else {
    flash_attn<0><<<dim3(16, 16, 2), 256, 0, stream>>>(qkb, vtb, ob,
                                                       nullptr, nullptr);
  }
  gemm_bt<1><<<dim3(8, 32), 256, 0, stream>>>(ob, WprojT, out, nullptr, bproj,
                                              M_, DIM_, DIM_, DIM_,
                                              nullptr, nullptr, nullptr, nullptr);
}